// Round 11
// baseline (13005.458 us; speedup 1.0000x reference)
//
#include <hip/hip_runtime.h>
#include <hip/hip_bf16.h>

// ---------------- constants ----------------
static constexpr int kT    = 2048;
static constexpr int kOUT_ELEMS = 2048 * 4096;   // output 0 size

typedef _Float16 half2_t __attribute__((ext_vector_type(2)));

__device__ __forceinline__ unsigned pack_h2(float a, float b) {
  half2_t h{(_Float16)a, (_Float16)b};
  return __builtin_bit_cast(unsigned, h);
}
__device__ __forceinline__ float fdot2u(unsigned a, unsigned b, float c) {
  return __builtin_amdgcn_fdot2(__builtin_bit_cast(half2_t, a),
                                __builtin_bit_cast(half2_t, b), c, false);
}
__device__ __forceinline__ float sigm(float x) {
  return 1.f / (1.f + __expf(-x));
}
__device__ __forceinline__ float tanh_f(float x) {
  float ax = fabsf(x);
  float e = __expf(-2.f * ax);
  float r = (1.f - e) / (1.f + e);
  return x < 0.f ? -r : r;
}

// LSTM per-(row,q)-thread weight split: 64 half2 total
static constexpr int NV = 40;   // VGPR half2 (10 uint4 chunks)
static constexpr int NL = 24;   // LDS half2  (6 chunks), slab stride 28 u32 (16B aligned, 8 bank-starts)

// ---------------- K0: prep ----------------
// wprep3 [ld<4][p<2][e<64][j<1024]: weight half2 e for the thread j of block (ld,p)
//   thread j: w=j>>6, l=j&63, q=l>>5, lh=l&31, r_local=w*32+lh, gate=r_local>>7,
//   m=r_local&127, R=gate*256+128p+m, cols {2*(64q+e), +1}
// wgru [g2<2][e<64][row<384]: fp16 GRU Whh (dir0)
__global__ __launch_bounds__(256) void prep_kernel(
    const float* __restrict__ enc_Wih, const float* __restrict__ enc_bih,
    const float* __restrict__ cenc_Wih, const float* __restrict__ cenc_bih,
    const float* __restrict__ enc_Whh, const float* __restrict__ cenc_Whh,
    const float* __restrict__ l0_Whh, const float* __restrict__ l1_Whh,
    const float* __restrict__ l0_bih, const float* __restrict__ l0_bhh,
    const float* __restrict__ l1_bih, const float* __restrict__ l1_bhh,
    float* __restrict__ wcat, float* __restrict__ bcat,
    float* __restrict__ bias0, float* __restrict__ bias1,
    unsigned* __restrict__ wprep3, unsigned* __restrict__ wgru,
    unsigned* __restrict__ flagsg) {
  int idx0 = blockIdx.x * blockDim.x + threadIdx.x;
  int stride = gridDim.x * blockDim.x;
  for (int i = idx0; i < 8; i += stride) flagsg[i] = 0u;   // re-zero every launch
  for (int i = idx0; i < 768 * 1024; i += stride) {
    int r = i >> 10, cc = i & 1023;
    wcat[i] = (r < 384) ? enc_Wih[r * 1024 + cc] : cenc_Wih[(r - 384) * 1024 + cc];
  }
  for (int i = idx0; i < 768; i += stride)
    bcat[i] = (i < 384) ? enc_bih[i] : cenc_bih[i - 384];
  for (int i = idx0; i < 2048; i += stride) {
    bias0[i] = l0_bih[i] + l0_bhh[i];
    bias1[i] = l1_bih[i] + l1_bhh[i];
  }
  for (int i = idx0; i < 4 * 2 * 64 * 1024; i += stride) {
    int j = i & 1023;
    int e = (i >> 10) & 63;
    int p = (i >> 16) & 1;
    int ld = i >> 17;  // layer*2 + dir
    const float* W = (ld < 2 ? l0_Whh : l1_Whh) + (ld & 1) * 1024 * 256;
    int w = j >> 6, l = j & 63;
    int q = l >> 5, lh = l & 31;
    int r_local = w * 32 + lh;
    int gate = r_local >> 7, m = r_local & 127;
    int R = gate * 256 + 128 * p + m;
    int col = 2 * (64 * q + e);
    wprep3[i] = pack_h2(W[R * 256 + col], W[R * 256 + col + 1]);
  }
  for (int i = idx0; i < 2 * 64 * 384; i += stride) {
    int row = i % 384;
    int e = (i / 384) & 63;
    int g2 = i / (64 * 384);
    const float* W = g2 ? cenc_Whh : enc_Whh;   // dir0 at base
    wgru[i] = pack_h2(W[row * 128 + 2 * e], W[row * 128 + 2 * e + 1]);
  }
}

// ---------------- fp32 tiled GEMM: C[M][N] = A[M][K] * B[N][K]^T + bias[N] ----------------
__global__ __launch_bounds__(256) void gemm_bt(
    const float* __restrict__ A, const float* __restrict__ B,
    const float* __restrict__ bias, float* __restrict__ C,
    int M, int N, int K) {
  __shared__ float As[16][68];
  __shared__ float Bs[16][68];
  int tid = threadIdx.x;
  int tx = tid & 15, ty = tid >> 4;
  int m0 = blockIdx.y * 64, n0 = blockIdx.x * 64;
  int lr = tid >> 2;
  int lc = (tid & 3) << 2;
  float acc[4][4] = {};
  const float* Ap = A + (long)(m0 + lr) * K + lc;
  const float* Bp = B + (long)(n0 + lr) * K + lc;
  for (int k0 = 0; k0 < K; k0 += 16) {
    float4 a4 = *(const float4*)(Ap + k0);
    float4 b4 = *(const float4*)(Bp + k0);
    __syncthreads();
    As[lc + 0][lr] = a4.x; As[lc + 1][lr] = a4.y; As[lc + 2][lr] = a4.z; As[lc + 3][lr] = a4.w;
    Bs[lc + 0][lr] = b4.x; Bs[lc + 1][lr] = b4.y; Bs[lc + 2][lr] = b4.z; Bs[lc + 3][lr] = b4.w;
    __syncthreads();
#pragma unroll
    for (int kk = 0; kk < 16; kk++) {
      float4 ra = *(const float4*)&As[kk][ty << 2];
      float4 rb = *(const float4*)&Bs[kk][tx << 2];
      float av[4] = {ra.x, ra.y, ra.z, ra.w};
      float bv[4] = {rb.x, rb.y, rb.z, rb.w};
#pragma unroll
      for (int i = 0; i < 4; i++)
#pragma unroll
        for (int jj = 0; jj < 4; jj++)
          acc[i][jj] += av[i] * bv[jj];
    }
  }
#pragma unroll
  for (int i = 0; i < 4; i++) {
    int m = m0 + (ty << 2) + i;
#pragma unroll
    for (int jj = 0; jj < 4; jj++) {
      int n = n0 + (tx << 2) + jj;
      C[(long)m * N + n] = acc[i][jj] + (bias ? bias[n] : 0.f);
    }
  }
}

// ---------------- GRU: 256 threads, fp16 weights fully VGPR-resident ----------------
__global__ __launch_bounds__(256) void gru2(
    const float* __restrict__ xgg,   // [T][768]
    const float* __restrict__ c_in,  // [T][1024]
    const unsigned* __restrict__ wgru,
    const float* __restrict__ enc_Wih, const float* __restrict__ enc_bih,
    const float* __restrict__ enc_bhh,
    const float* __restrict__ cenc_Wih, const float* __restrict__ cenc_bih,
    const float* __restrict__ cenc_bhh,
    float* __restrict__ u_out, float* __restrict__ cmem_out) {
  int b = blockIdx.x, j = threadIdx.x;
  __shared__ __align__(16) unsigned h2g[64];
  __shared__ float zs[128];
  const bool dual = j < 128;
  if (b < 2) {
    const unsigned* wg = wgru + b * (64 * 384);
    const float* bhh = b ? cenc_bhh : enc_bhh;
    unsigned w0[64], w1[64];
#pragma unroll
    for (int e = 0; e < 64; ++e) w0[e] = wg[e * 384 + j];
    float bh0 = bhh[j], bh1 = 0.f;
    if (dual) {
#pragma unroll
      for (int e = 0; e < 64; ++e) w1[e] = wg[e * 384 + 256 + j];
      bh1 = bhh[256 + j];
    }
    if (j < 64) h2g[j] = 0u;
    float hreg = 0.f;
    __syncthreads();
    const float* xp = xgg + b * 384;
    float x0 = xp[j];
    float x1 = dual ? xp[256 + j] : 0.f;
    for (int t = 0; t < kT; ++t) {
      float x0n = 0.f, x1n = 0.f;
      if (t + 1 < kT) {
        x0n = xp[(t + 1) * 768 + j];
        if (dual) x1n = xp[(t + 1) * 768 + 256 + j];
      }
      const uint4* h4 = (const uint4*)h2g;
      float a0 = 0.f, a1 = 0.f;
#pragma unroll
      for (int k = 0; k < 16; ++k) {
        uint4 hh = h4[k];
        a0 = fdot2u(w0[4 * k + 0], hh.x, a0);
        a0 = fdot2u(w0[4 * k + 1], hh.y, a0);
        a0 = fdot2u(w0[4 * k + 2], hh.z, a0);
        a0 = fdot2u(w0[4 * k + 3], hh.w, a0);
        if (dual) {
          a1 = fdot2u(w1[4 * k + 0], hh.x, a1);
          a1 = fdot2u(w1[4 * k + 1], hh.y, a1);
          a1 = fdot2u(w1[4 * k + 2], hh.z, a1);
          a1 = fdot2u(w1[4 * k + 3], hh.w, a1);
        }
      }
      if (!dual) zs[j - 128] = sigm(x0 + a0 + bh0);
      __syncthreads();
      if (dual) {
        float r = sigm(x0 + a0 + bh0);
        float n = tanh_f(x1 + r * (a1 + bh1));
        float z = zs[j];
        hreg = (1.f - z) * n + z * hreg;
        float hx = __shfl_xor(hreg, 1);
        if (!(j & 1)) h2g[j >> 1] = pack_h2(hreg, hx);
      }
      __syncthreads();
      x0 = x0n; x1 = x1n;
    }
    if (dual) { if (b == 0) u_out[j] = hreg; else cmem_out[j] = hreg; }
  } else {
    const float* Wih = ((b == 2) ? enc_Wih : cenc_Wih) + 384 * 1024;
    const float* bih = ((b == 2) ? enc_bih : cenc_bih) + 384;
    const float* bhh = ((b == 2) ? enc_bhh : cenc_bhh) + 384;
    const float* crow = c_in + (long)(kT - 1) * 1024;
    float a0 = bih[j], a1 = 0.f;
    {
      const float* wr = Wih + (long)j * 1024;
      for (int k = 0; k < 1024; k += 4) {
        float4 cv = *(const float4*)&crow[k];
        float4 wv = *(const float4*)&wr[k];
        a0 += cv.x * wv.x + cv.y * wv.y + cv.z * wv.z + cv.w * wv.w;
      }
    }
    if (dual) {
      a1 = bih[256 + j];
      const float* wr = Wih + (long)(256 + j) * 1024;
      for (int k = 0; k < 1024; k += 4) {
        float4 cv = *(const float4*)&crow[k];
        float4 wv = *(const float4*)&wr[k];
        a1 += cv.x * wv.x + cv.y * wv.y + cv.z * wv.z + cv.w * wv.w;
      }
    }
    if (!dual) zs[j - 128] = sigm(a0 + bhh[j]);
    __syncthreads();
    if (dual) {
      float r = sigm(a0 + bhh[j]);
      float n = tanh_f(a1 + r * bhh[256 + j]);
      float z = zs[j];
      float h = (1.f - z) * n;
      if (b == 2) u_out[128 + j] = h; else cmem_out[128 + j] = h;
    }
  }
}

// ---------------- attention ----------------
__global__ __launch_bounds__(256) void attn_dots(
    const float* __restrict__ mem, const float* __restrict__ u, float* __restrict__ d) {
  __shared__ float us[256];
  int tid = threadIdx.x;
  us[tid] = u[tid];
  __syncthreads();
  int g = tid >> 3, l8 = tid & 7;
  int row = blockIdx.x * 32 + g;
  const float* mr = mem + (long)row * 256 + l8 * 32;
  float p = 0.f;
#pragma unroll
  for (int k = 0; k < 32; k += 4) {
    float4 m4 = *(const float4*)&mr[k];
    p += m4.x * us[l8 * 32 + k] + m4.y * us[l8 * 32 + k + 1] +
         m4.z * us[l8 * 32 + k + 2] + m4.w * us[l8 * 32 + k + 3];
  }
  p += __shfl_down(p, 4);
  p += __shfl_down(p, 2);
  p += __shfl_down(p, 1);
  if (l8 == 0) d[row] = p;
}

__global__ __launch_bounds__(1024) void attn_soft(
    const float* __restrict__ d, float* __restrict__ p, float* __restrict__ h_acc) {
  __shared__ float red[1024];
  int tid = threadIdx.x;
  float v[8];
  float mx = -1e30f;
#pragma unroll
  for (int i = 0; i < 8; i++) { v[i] = d[tid * 8 + i]; mx = fmaxf(mx, v[i]); }
  red[tid] = mx; __syncthreads();
  for (int s = 512; s > 0; s >>= 1) {
    if (tid < s) red[tid] = fmaxf(red[tid], red[tid + s]);
    __syncthreads();
  }
  mx = red[0]; __syncthreads();
  float sm = 0.f; float e[8];
#pragma unroll
  for (int i = 0; i < 8; i++) { e[i] = __expf(v[i] - mx); sm += e[i]; }
  red[tid] = sm; __syncthreads();
  for (int s = 512; s > 0; s >>= 1) {
    if (tid < s) red[tid] += red[tid + s];
    __syncthreads();
  }
  float rz = 1.f / red[0];
#pragma unroll
  for (int i = 0; i < 8; i++) p[tid * 8 + i] = e[i] * rz;
  if (tid < 256) h_acc[tid] = 0.f;
}

__global__ __launch_bounds__(256) void attn_h(
    const float* __restrict__ mem, const float* __restrict__ p, float* __restrict__ h_acc) {
  int tid = threadIdx.x;
  int r0 = blockIdx.x * 128;
  float acc = 0.f;
  for (int i = 0; i < 128; i++) acc += p[r0 + i] * mem[(long)(r0 + i) * 256 + tid];
  atomicAdd(&h_acc[tid], acc);
}

__global__ __launch_bounds__(128) void attn_o(
    const float* __restrict__ u, const float* __restrict__ h_acc,
    const float* __restrict__ know_W, const float* __restrict__ know_b,
    float* __restrict__ o) {
  __shared__ float uh[256];
  int tid = threadIdx.x;
  uh[tid] = u[tid] + h_acc[tid];
  uh[128 + tid] = u[128 + tid] + h_acc[128 + tid];
  __syncthreads();
  int row = blockIdx.x * 128 + tid;
  float acc = know_b[row];
  for (int k = 0; k < 256; k += 4) {
    float4 w4 = *(const float4*)&know_W[row * 256 + k];
    acc += w4.x * uh[k] + w4.y * uh[k + 1] + w4.z * uh[k + 2] + w4.w * uh[k + 3];
  }
  o[row] = acc;
}

__global__ __launch_bounds__(128) void attn_ov(
    const float* __restrict__ o, const float* __restrict__ Wih0, float* __restrict__ ov) {
  int row = blockIdx.x * 128 + threadIdx.x;
  float acc = 0.f;
  for (int k = 0; k < 1024; k += 4) {
    float4 w4 = *(const float4*)&Wih0[(long)row * 1024 + k];
    float4 o4 = *(const float4*)&o[k];
    acc += w4.x * o4.x + w4.y * o4.y + w4.z * o4.z + w4.w * o4.w;
  }
  ov[row] = acc;
}

// ---------------- LSTM v11: 2 CUs per direction, all weights on-chip ----------------
// grid = 4: block (dir = bid>>1, p = bid&1) owns h-elems [128p,128p+128) = 512 gate rows.
// Per thread (1024 thr): one (row, K-half): 40 half2 VGPR + 24 LDS. 117 KB LDS -> 1 block/CU.
// Per-step h-half exchange via agent-scope atomics (payload 64 u32 double-buffered,
// flag = s+1 monotone; zeroed each launch in prep; spin capped to avoid hangs).
__global__ __launch_bounds__(1024) void lstm_cc(
    const unsigned* __restrict__ wp3,    // layer base: [(dir*2+p)*64 + e][1024]
    const float* __restrict__ xg,        // [T][2048] (biases folded)
    const float* __restrict__ extra,     // [2048] rank-1 add or nullptr
    float* __restrict__ out,             // [T][512]
    unsigned* __restrict__ pay,          // layer base: [(dir*2+p)][slot<2][64]
    unsigned* __restrict__ flg) {        // layer base: [(dir*2+p)]
  const int bid = blockIdx.x;
  const int dir = bid >> 1, p = bid & 1;
  const int j = threadIdx.x;
  const int l = j & 63, w = j >> 6;
  const int q = l >> 5;
  const int r_local = w * 32 + (l & 31);           // [0,512)
  const int gate = r_local >> 7;                   // wave-uniform
  const int m = r_local & 127;
  const int R = gate * 256 + 128 * p + m;          // global gate row

  __shared__ __align__(16) unsigned wl[1024 * 28]; // 114688 B
  __shared__ float gact[512];                      // 2 KB
  __shared__ __align__(16) unsigned h2v[128];      // full h packed

  const unsigned* base = wp3 + (size_t)((dir * 2 + p) * 64) * 1024;
  // LDS slab fill: e in [NV,64)
  for (int e = NV; e < 64; ++e)
    wl[j * 28 + (e - NV)] = base[e * 1024 + j];
  unsigned wv[NV];
#pragma unroll
  for (int e = 0; e < NV; ++e) wv[e] = base[e * 1024 + j];

  float exv = extra ? extra[dir * 1024 + R] : 0.f;
  if (j < 128) h2v[j] = 0u;
  float cst = 0.f;
  __syncthreads();

  unsigned* mypay = pay + (dir * 2 + p) * 128;
  unsigned* peerpay = pay + (dir * 2 + (1 - p)) * 128;
  unsigned* myflg = flg + (dir * 2 + p);
  unsigned* peerflg = flg + (dir * 2 + (1 - p));

  const float* xp = xg + dir * 1024;
  const int t0 = dir ? (kT - 1) : 0;
  const int dt = dir ? -1 : 1;
  float xc = xp[(long)t0 * 2048 + R] + exv;

  for (int s = 0; s < kT; ++s) {
    const int t = t0 + s * dt;
    float xn_ = 0.f;
    if (s + 1 < kT) xn_ = xp[(long)(t + dt) * 2048 + R];
    // consume peer's h-half of step s (published with flag value s)
    if (j < 64 && s > 0) {
      unsigned fv;
      int guard = 0;
      do {
        unsigned x = 0;
        if (j == 0)
          x = __hip_atomic_load(peerflg, __ATOMIC_ACQUIRE, __HIP_MEMORY_SCOPE_AGENT);
        fv = __shfl(x, 0);
      } while (fv < (unsigned)s && ++guard < (1 << 27));
      unsigned pv = __hip_atomic_load(&peerpay[(s & 1) * 64 + j],
                                      __ATOMIC_RELAXED, __HIP_MEMORY_SCOPE_AGENT);
      h2v[64 * (1 - p) + j] = pv;
    }
    __syncthreads();
    // dot over this thread's K-half
    const uint4* h4 = ((const uint4*)h2v) + q * 16;
    float acc = 0.f;
#pragma unroll
    for (int c = 0; c < NV / 4; ++c) {
      uint4 hh = h4[c];
      acc = fdot2u(wv[4 * c + 0], hh.x, acc);
      acc = fdot2u(wv[4 * c + 1], hh.y, acc);
      acc = fdot2u(wv[4 * c + 2], hh.z, acc);
      acc = fdot2u(wv[4 * c + 3], hh.w, acc);
    }
#pragma unroll
    for (int c = 0; c < NL / 4; ++c) {
      uint4 hh = h4[NV / 4 + c];
      uint4 qw = *(const uint4*)&wl[j * 28 + 4 * c];
      acc = fdot2u(qw.x, hh.x, acc);
      acc = fdot2u(qw.y, hh.y, acc);
      acc = fdot2u(qw.z, hh.z, acc);
      acc = fdot2u(qw.w, hh.w, acc);
    }
    float sfull = acc + __shfl_xor(acc, 32);
    float sv = sfull + xc;
    float act = (gate == 2) ? tanh_f(sv) : sigm(sv);
    if (q == 0) gact[r_local] = act;
    __syncthreads();
    if (j < 128) {
      float iv  = gact[j];
      float fv  = gact[128 + j];
      float gv  = gact[256 + j];
      float ovv = gact[384 + j];
      cst = fv * cst + iv * gv;
      float h = ovv * tanh_f(cst);
      out[(long)t * 512 + dir * 256 + 128 * p + j] = h;
      float hx = __shfl_xor(h, 1);
      if (!(j & 1)) {
        int idx = j >> 1;                       // 0..63
        unsigned hp = pack_h2(h, hx);
        h2v[64 * p + idx] = hp;
        __hip_atomic_store(&mypay[((s + 1) & 1) * 64 + idx], hp,
                           __ATOMIC_RELAXED, __HIP_MEMORY_SCOPE_AGENT);
      }
    }
    __syncthreads();   // payload stores drained (vmcnt) before flag
    if (j == 0) {
      __threadfence();
      __hip_atomic_store(myflg, (unsigned)(s + 1),
                         __ATOMIC_RELEASE, __HIP_MEMORY_SCOPE_AGENT);
    }
    xc = xn_ + exv;
  }
}

// ---------------- final row softmax ----------------
__global__ __launch_bounds__(256) void softmax_rows(
    const float* __restrict__ logits, float* __restrict__ outp) {
  int t = blockIdx.x, tid = threadIdx.x;
  __shared__ float red[256];
  const float* lr = logits + (long)t * 4096;
  float v[16];
  float mx = -1e30f;
#pragma unroll
  for (int i = 0; i < 16; i++) { v[i] = lr[tid + 256 * i]; mx = fmaxf(mx, v[i]); }
  red[tid] = mx; __syncthreads();
  for (int s = 128; s > 0; s >>= 1) {
    if (tid < s) red[tid] = fmaxf(red[tid], red[tid + s]);
    __syncthreads();
  }
  mx = red[0]; __syncthreads();
  float sm = 0.f;
#pragma unroll
  for (int i = 0; i < 16; i++) { v[i] = __expf(v[i] - mx); sm += v[i]; }
  red[tid] = sm; __syncthreads();
  for (int s = 128; s > 0; s >>= 1) {
    if (tid < s) red[tid] += red[tid + s];
    __syncthreads();
  }
  float rz = 1.f / red[0];
#pragma unroll
  for (int i = 0; i < 16; i++) outp[(long)t * 4096 + tid + 256 * i] = v[i] * rz;
}

// ---------------- launch ----------------
extern "C" void kernel_launch(void* const* d_in, const int* in_sizes, int n_in,
                              void* d_out, int out_size, void* d_ws, size_t ws_size,
                              hipStream_t stream) {
  const float* c        = (const float*)d_in[0];
  const float* memory   = (const float*)d_in[1];
  const float* enc_Wih  = (const float*)d_in[2];
  const float* enc_Whh  = (const float*)d_in[3];
  const float* enc_bih  = (const float*)d_in[4];
  const float* enc_bhh  = (const float*)d_in[5];
  const float* cenc_Wih = (const float*)d_in[6];
  const float* cenc_Whh = (const float*)d_in[7];
  const float* cenc_bih = (const float*)d_in[8];
  const float* cenc_bhh = (const float*)d_in[9];
  const float* know_W   = (const float*)d_in[10];
  const float* know_b   = (const float*)d_in[11];
  const float* l0_Wih   = (const float*)d_in[12];
  const float* l0_Whh   = (const float*)d_in[13];
  const float* l0_bih   = (const float*)d_in[14];
  const float* l0_bhh   = (const float*)d_in[15];
  const float* l1_Wih   = (const float*)d_in[16];
  const float* l1_Whh   = (const float*)d_in[17];
  const float* l1_bih   = (const float*)d_in[18];
  const float* l1_bhh   = (const float*)d_in[19];
  const float* out_W    = (const float*)d_in[20];
  const float* out_b    = (const float*)d_in[21];

  float* ws = (float*)d_ws;
  float* outp = (float*)d_out;

  float* xgg   = ws;                  // 1,572,864   [T][768]
  float* cW    = ws + 1572864;        // 4,194,304   [T][2048]
  float* wcat  = ws + 5767168;        //   786,432
  float* l0out = ws + 6553600;        // 1,048,576   [T][512]
  float* xg1   = ws + 7602176;        // 4,194,304   [T][2048]
  unsigned* wprep3 = (unsigned*)(ws + 11796480);  // 524,288 u32 (2 MB)
  float* bcat  = ws + 12320768;       // 768
  float* bias0 = ws + 12321536;       // 2048
  float* bias1 = ws + 12323584;       // 2048
  float* u_vec = ws + 12325632;       // 256
  float* d_att = ws + 12325888;       // 8192
  float* p_att = ws + 12334080;       // 8192
  float* h_acc = ws + 12342272;       // 256
  float* o_vec = ws + 12342528;       // 1024
  float* ov    = ws + 12343552;       // 2048
  float* l1out = ws + 12345600;       // 1,048,576  (ends 13,394,176)
  unsigned* wgru = (unsigned*)(ws + 13656320);      // 49,152 u32
  unsigned* payload = (unsigned*)(ws + 13705472);   // 1024 u32 (2 layers × 4 × 128)
  unsigned* flagsg  = (unsigned*)(ws + 13706496);   // 8 u32
  float* logits = ws;                 // 8,388,608   aliases early regions

  prep_kernel<<<512, 256, 0, stream>>>(enc_Wih, enc_bih, cenc_Wih, cenc_bih,
                                       enc_Whh, cenc_Whh,
                                       l0_Whh, l1_Whh, l0_bih, l0_bhh, l1_bih, l1_bhh,
                                       wcat, bcat, bias0, bias1, wprep3, wgru, flagsg);
  gemm_bt<<<dim3(768 / 64, 2048 / 64), 256, 0, stream>>>(c, wcat, bcat, xgg, 2048, 768, 1024);
  gemm_bt<<<dim3(2048 / 64, 2048 / 64), 256, 0, stream>>>(c, l0_Wih, bias0, cW, 2048, 2048, 1024);
  gru2<<<4, 256, 0, stream>>>(xgg, c, wgru, enc_Wih, enc_bih, enc_bhh,
                              cenc_Wih, cenc_bih, cenc_bhh,
                              u_vec, outp + kOUT_ELEMS);
  attn_dots<<<256, 256, 0, stream>>>(memory, u_vec, d_att);
  attn_soft<<<1, 1024, 0, stream>>>(d_att, p_att, h_acc);
  attn_h<<<64, 256, 0, stream>>>(memory, p_att, h_acc);
  attn_o<<<8, 128, 0, stream>>>(u_vec, h_acc, know_W, know_b, o_vec);
  attn_ov<<<16, 128, 0, stream>>>(o_vec, l0_Wih, ov);
  lstm_cc<<<4, 1024, 0, stream>>>(wprep3, cW, ov, l0out, payload, flagsg);
  gemm_bt<<<dim3(2048 / 64, 2048 / 64), 256, 0, stream>>>(l0out, l1_Wih, bias1, xg1, 2048, 2048, 512);
  lstm_cc<<<4, 1024, 0, stream>>>(wprep3 + 262144, xg1, nullptr, l1out,
                                  payload + 512, flagsg + 4);
  gemm_bt<<<dim3(4096 / 64, 2048 / 64), 256, 0, stream>>>(l1out, out_W, out_b, logits, 2048, 4096, 512);
  softmax_rows<<<2048, 256, 0, stream>>>(logits, outp);
}

// Round 13
// 8308.064 us; speedup vs baseline: 1.5654x; 1.5654x over previous
//
#include <hip/hip_runtime.h>
#include <hip/hip_bf16.h>

// ---------------- constants ----------------
static constexpr int kT    = 2048;
static constexpr int kOUT_ELEMS = 2048 * 4096;   // output 0 size

typedef _Float16 half2_t __attribute__((ext_vector_type(2)));
typedef unsigned long long u64;

__device__ __forceinline__ unsigned pack_h2(float a, float b) {
  half2_t h{(_Float16)a, (_Float16)b};
  return __builtin_bit_cast(unsigned, h);
}
__device__ __forceinline__ float fdot2u(unsigned a, unsigned b, float c) {
  return __builtin_amdgcn_fdot2(__builtin_bit_cast(half2_t, a),
                                __builtin_bit_cast(half2_t, b), c, false);
}
__device__ __forceinline__ float sigm(float x) {
  return 1.f / (1.f + __expf(-x));
}
__device__ __forceinline__ float tanh_f(float x) {
  float ax = fabsf(x);
  float e = __expf(-2.f * ax);
  float r = (1.f - e) / (1.f + e);
  return x < 0.f ? -r : r;
}

// LSTM per-(row,q)-thread weight split: 64 half2 total
static constexpr int NV = 40;   // VGPR half2 (10 uint4 chunks)
static constexpr int NL = 24;   // LDS half2  (6 chunks), slab stride 28 u32

// ---------------- K0: prep ----------------
// wprep3 [ld<4][p<2][e<64][j<1024]; wgru [g2<2][e<64][row<384]; payload tags zeroed.
__global__ __launch_bounds__(256) void prep_kernel(
    const float* __restrict__ enc_Wih, const float* __restrict__ enc_bih,
    const float* __restrict__ cenc_Wih, const float* __restrict__ cenc_bih,
    const float* __restrict__ enc_Whh, const float* __restrict__ cenc_Whh,
    const float* __restrict__ l0_Whh, const float* __restrict__ l1_Whh,
    const float* __restrict__ l0_bih, const float* __restrict__ l0_bhh,
    const float* __restrict__ l1_bih, const float* __restrict__ l1_bhh,
    float* __restrict__ wcat, float* __restrict__ bcat,
    float* __restrict__ bias0, float* __restrict__ bias1,
    unsigned* __restrict__ wprep3, unsigned* __restrict__ wgru,
    u64* __restrict__ payz) {
  int idx0 = blockIdx.x * blockDim.x + threadIdx.x;
  int stride = gridDim.x * blockDim.x;
  for (int i = idx0; i < 1024; i += stride) payz[i] = 0ull;   // re-zero every launch
  for (int i = idx0; i < 768 * 1024; i += stride) {
    int r = i >> 10, cc = i & 1023;
    wcat[i] = (r < 384) ? enc_Wih[r * 1024 + cc] : cenc_Wih[(r - 384) * 1024 + cc];
  }
  for (int i = idx0; i < 768; i += stride)
    bcat[i] = (i < 384) ? enc_bih[i] : cenc_bih[i - 384];
  for (int i = idx0; i < 2048; i += stride) {
    bias0[i] = l0_bih[i] + l0_bhh[i];
    bias1[i] = l1_bih[i] + l1_bhh[i];
  }
  for (int i = idx0; i < 4 * 2 * 64 * 1024; i += stride) {
    int j = i & 1023;
    int e = (i >> 10) & 63;
    int p = (i >> 16) & 1;
    int ld = i >> 17;  // layer*2 + dir
    const float* W = (ld < 2 ? l0_Whh : l1_Whh) + (ld & 1) * 1024 * 256;
    int w = j >> 6, l = j & 63;
    int q = l >> 5, lh = l & 31;
    int r_local = w * 32 + lh;
    int gate = r_local >> 7, m = r_local & 127;
    int R = gate * 256 + 128 * p + m;
    int col = 2 * (64 * q + e);
    wprep3[i] = pack_h2(W[R * 256 + col], W[R * 256 + col + 1]);
  }
  for (int i = idx0; i < 2 * 64 * 384; i += stride) {
    int row = i % 384;
    int e = (i / 384) & 63;
    int g2 = i / (64 * 384);
    const float* W = g2 ? cenc_Whh : enc_Whh;   // dir0 at base
    wgru[i] = pack_h2(W[row * 128 + 2 * e], W[row * 128 + 2 * e + 1]);
  }
}

// ---------------- fp32 tiled GEMM: C[M][N] = A[M][K] * B[N][K]^T + bias[N] ----------------
__global__ __launch_bounds__(256) void gemm_bt(
    const float* __restrict__ A, const float* __restrict__ B,
    const float* __restrict__ bias, float* __restrict__ C,
    int M, int N, int K) {
  __shared__ float As[16][68];
  __shared__ float Bs[16][68];
  int tid = threadIdx.x;
  int tx = tid & 15, ty = tid >> 4;
  int m0 = blockIdx.y * 64, n0 = blockIdx.x * 64;
  int lr = tid >> 2;
  int lc = (tid & 3) << 2;
  float acc[4][4] = {};
  const float* Ap = A + (long)(m0 + lr) * K + lc;
  const float* Bp = B + (long)(n0 + lr) * K + lc;
  for (int k0 = 0; k0 < K; k0 += 16) {
    float4 a4 = *(const float4*)(Ap + k0);
    float4 b4 = *(const float4*)(Bp + k0);
    __syncthreads();
    As[lc + 0][lr] = a4.x; As[lc + 1][lr] = a4.y; As[lc + 2][lr] = a4.z; As[lc + 3][lr] = a4.w;
    Bs[lc + 0][lr] = b4.x; Bs[lc + 1][lr] = b4.y; Bs[lc + 2][lr] = b4.z; Bs[lc + 3][lr] = b4.w;
    __syncthreads();
#pragma unroll
    for (int kk = 0; kk < 16; kk++) {
      float4 ra = *(const float4*)&As[kk][ty << 2];
      float4 rb = *(const float4*)&Bs[kk][tx << 2];
      float av[4] = {ra.x, ra.y, ra.z, ra.w};
      float bv[4] = {rb.x, rb.y, rb.z, rb.w};
#pragma unroll
      for (int i = 0; i < 4; i++)
#pragma unroll
        for (int jj = 0; jj < 4; jj++)
          acc[i][jj] += av[i] * bv[jj];
    }
  }
#pragma unroll
  for (int i = 0; i < 4; i++) {
    int m = m0 + (ty << 2) + i;
#pragma unroll
    for (int jj = 0; jj < 4; jj++) {
      int n = n0 + (tx << 2) + jj;
      C[(long)m * N + n] = acc[i][jj] + (bias ? bias[n] : 0.f);
    }
  }
}

// ---------------- GRU: 256 threads, fp16 weights fully VGPR-resident ----------------
__global__ __launch_bounds__(256) void gru2(
    const float* __restrict__ xgg,   // [T][768]
    const float* __restrict__ c_in,  // [T][1024]
    const unsigned* __restrict__ wgru,
    const float* __restrict__ enc_Wih, const float* __restrict__ enc_bih,
    const float* __restrict__ enc_bhh,
    const float* __restrict__ cenc_Wih, const float* __restrict__ cenc_bih,
    const float* __restrict__ cenc_bhh,
    float* __restrict__ u_out, float* __restrict__ cmem_out) {
  int b = blockIdx.x, j = threadIdx.x;
  __shared__ __align__(16) unsigned h2g[64];
  __shared__ float zs[128];
  const bool dual = j < 128;
  if (b < 2) {
    const unsigned* wg = wgru + b * (64 * 384);
    const float* bhh = b ? cenc_bhh : enc_bhh;
    unsigned w0[64], w1[64];
#pragma unroll
    for (int e = 0; e < 64; ++e) w0[e] = wg[e * 384 + j];
    float bh0 = bhh[j], bh1 = 0.f;
    if (dual) {
#pragma unroll
      for (int e = 0; e < 64; ++e) w1[e] = wg[e * 384 + 256 + j];
      bh1 = bhh[256 + j];
    }
    if (j < 64) h2g[j] = 0u;
    float hreg = 0.f;
    __syncthreads();
    const float* xp = xgg + b * 384;
    float x0 = xp[j];
    float x1 = dual ? xp[256 + j] : 0.f;
    for (int t = 0; t < kT; ++t) {
      float x0n = 0.f, x1n = 0.f;
      if (t + 1 < kT) {
        x0n = xp[(t + 1) * 768 + j];
        if (dual) x1n = xp[(t + 1) * 768 + 256 + j];
      }
      const uint4* h4 = (const uint4*)h2g;
      float a0 = 0.f, a1 = 0.f;
#pragma unroll
      for (int k = 0; k < 16; ++k) {
        uint4 hh = h4[k];
        a0 = fdot2u(w0[4 * k + 0], hh.x, a0);
        a0 = fdot2u(w0[4 * k + 1], hh.y, a0);
        a0 = fdot2u(w0[4 * k + 2], hh.z, a0);
        a0 = fdot2u(w0[4 * k + 3], hh.w, a0);
        if (dual) {
          a1 = fdot2u(w1[4 * k + 0], hh.x, a1);
          a1 = fdot2u(w1[4 * k + 1], hh.y, a1);
          a1 = fdot2u(w1[4 * k + 2], hh.z, a1);
          a1 = fdot2u(w1[4 * k + 3], hh.w, a1);
        }
      }
      if (!dual) zs[j - 128] = sigm(x0 + a0 + bh0);
      __syncthreads();
      if (dual) {
        float r = sigm(x0 + a0 + bh0);
        float n = tanh_f(x1 + r * (a1 + bh1));
        float z = zs[j];
        hreg = (1.f - z) * n + z * hreg;
        float hx = __shfl_xor(hreg, 1);
        if (!(j & 1)) h2g[j >> 1] = pack_h2(hreg, hx);
      }
      __syncthreads();
      x0 = x0n; x1 = x1n;
    }
    if (dual) { if (b == 0) u_out[j] = hreg; else cmem_out[j] = hreg; }
  } else {
    const float* Wih = ((b == 2) ? enc_Wih : cenc_Wih) + 384 * 1024;
    const float* bih = ((b == 2) ? enc_bih : cenc_bih) + 384;
    const float* bhh = ((b == 2) ? enc_bhh : cenc_bhh) + 384;
    const float* crow = c_in + (long)(kT - 1) * 1024;
    float a0 = bih[j], a1 = 0.f;
    {
      const float* wr = Wih + (long)j * 1024;
      for (int k = 0; k < 1024; k += 4) {
        float4 cv = *(const float4*)&crow[k];
        float4 wv = *(const float4*)&wr[k];
        a0 += cv.x * wv.x + cv.y * wv.y + cv.z * wv.z + cv.w * wv.w;
      }
    }
    if (dual) {
      a1 = bih[256 + j];
      const float* wr = Wih + (long)(256 + j) * 1024;
      for (int k = 0; k < 1024; k += 4) {
        float4 cv = *(const float4*)&crow[k];
        float4 wv = *(const float4*)&wr[k];
        a1 += cv.x * wv.x + cv.y * wv.y + cv.z * wv.z + cv.w * wv.w;
      }
    }
    if (!dual) zs[j - 128] = sigm(a0 + bhh[j]);
    __syncthreads();
    if (dual) {
      float r = sigm(a0 + bhh[j]);
      float n = tanh_f(a1 + r * bhh[256 + j]);
      float z = zs[j];
      float h = (1.f - z) * n;
      if (b == 2) u_out[128 + j] = h; else cmem_out[128 + j] = h;
    }
  }
}

// ---------------- attention ----------------
__global__ __launch_bounds__(256) void attn_dots(
    const float* __restrict__ mem, const float* __restrict__ u, float* __restrict__ d) {
  __shared__ float us[256];
  int tid = threadIdx.x;
  us[tid] = u[tid];
  __syncthreads();
  int g = tid >> 3, l8 = tid & 7;
  int row = blockIdx.x * 32 + g;
  const float* mr = mem + (long)row * 256 + l8 * 32;
  float p = 0.f;
#pragma unroll
  for (int k = 0; k < 32; k += 4) {
    float4 m4 = *(const float4*)&mr[k];
    p += m4.x * us[l8 * 32 + k] + m4.y * us[l8 * 32 + k + 1] +
         m4.z * us[l8 * 32 + k + 2] + m4.w * us[l8 * 32 + k + 3];
  }
  p += __shfl_down(p, 4);
  p += __shfl_down(p, 2);
  p += __shfl_down(p, 1);
  if (l8 == 0) d[row] = p;
}

__global__ __launch_bounds__(1024) void attn_soft(
    const float* __restrict__ d, float* __restrict__ p, float* __restrict__ h_acc) {
  __shared__ float red[1024];
  int tid = threadIdx.x;
  float v[8];
  float mx = -1e30f;
#pragma unroll
  for (int i = 0; i < 8; i++) { v[i] = d[tid * 8 + i]; mx = fmaxf(mx, v[i]); }
  red[tid] = mx; __syncthreads();
  for (int s = 512; s > 0; s >>= 1) {
    if (tid < s) red[tid] = fmaxf(red[tid], red[tid + s]);
    __syncthreads();
  }
  mx = red[0]; __syncthreads();
  float sm = 0.f; float e[8];
#pragma unroll
  for (int i = 0; i < 8; i++) { e[i] = __expf(v[i] - mx); sm += e[i]; }
  red[tid] = sm; __syncthreads();
  for (int s = 512; s > 0; s >>= 1) {
    if (tid < s) red[tid] += red[tid + s];
    __syncthreads();
  }
  float rz = 1.f / red[0];
#pragma unroll
  for (int i = 0; i < 8; i++) p[tid * 8 + i] = e[i] * rz;
  if (tid < 256) h_acc[tid] = 0.f;
}

__global__ __launch_bounds__(256) void attn_h(
    const float* __restrict__ mem, const float* __restrict__ p, float* __restrict__ h_acc) {
  int tid = threadIdx.x;
  int r0 = blockIdx.x * 128;
  float acc = 0.f;
  for (int i = 0; i < 128; i++) acc += p[r0 + i] * mem[(long)(r0 + i) * 256 + tid];
  atomicAdd(&h_acc[tid], acc);
}

__global__ __launch_bounds__(128) void attn_o(
    const float* __restrict__ u, const float* __restrict__ h_acc,
    const float* __restrict__ know_W, const float* __restrict__ know_b,
    float* __restrict__ o) {
  __shared__ float uh[256];
  int tid = threadIdx.x;
  uh[tid] = u[tid] + h_acc[tid];
  uh[128 + tid] = u[128 + tid] + h_acc[128 + tid];
  __syncthreads();
  int row = blockIdx.x * 128 + tid;
  float acc = know_b[row];
  for (int k = 0; k < 256; k += 4) {
    float4 w4 = *(const float4*)&know_W[row * 256 + k];
    acc += w4.x * uh[k] + w4.y * uh[k + 1] + w4.z * uh[k + 2] + w4.w * uh[k + 3];
  }
  o[row] = acc;
}

__global__ __launch_bounds__(128) void attn_ov(
    const float* __restrict__ o, const float* __restrict__ Wih0, float* __restrict__ ov) {
  int row = blockIdx.x * 128 + threadIdx.x;
  float acc = 0.f;
  for (int k = 0; k < 1024; k += 4) {
    float4 w4 = *(const float4*)&Wih0[(long)row * 1024 + k];
    float4 o4 = *(const float4*)&o[k];
    acc += w4.x * o4.x + w4.y * o4.y + w4.z * o4.z + w4.w * o4.w;
  }
  ov[row] = acc;
}

// ---------------- LSTM v12: 2 CUs/direction, same-XCD pairing + tagged payload ----------------
// grid = 16; active blocks: bid&7 in {0,1} (dir = bid&7, p = bid>>3). Under the
// empirical bid%8 -> XCD round-robin this co-locates each pair on one XCD's L2.
// Per-step h-half exchange: single-RTT tagged uint64 payload {tag=s+1, h2} per lane,
// double-buffered by step parity. Tags zeroed in prep each launch (replay-safe).
// WAR-safe: blocks stay within 1 step of each other (mutual dependence).
// Spin guard 2^20/step: never approached in normal lockstep; bounds worst case.
__global__ __launch_bounds__(1024) void lstm_cc(
    const unsigned* __restrict__ wp3,    // layer base: [(dir*2+p)*64 + e][1024]
    const float* __restrict__ xg,        // [T][2048] (biases folded)
    const float* __restrict__ extra,     // [2048] rank-1 add or nullptr
    float* __restrict__ out,             // [T][512]
    u64* __restrict__ pay) {             // layer base: [(dir*2+p)][slot<2][64] u64
  const int bid = blockIdx.x;
  const int xs = bid & 7;
  if (xs >= 2) return;                   // inactive filler blocks
  const int dir = xs, p = bid >> 3;
  const int j = threadIdx.x;
  const int l = j & 63, w = j >> 6;
  const int q = l >> 5;
  const int r_local = w * 32 + (l & 31);           // [0,512)
  const int gate = r_local >> 7;                   // wave-uniform
  const int m = r_local & 127;
  const int R = gate * 256 + 128 * p + m;          // global gate row

  __shared__ __align__(16) unsigned wl[1024 * 28]; // 114688 B
  __shared__ float gact[512];                      // 2 KB
  __shared__ __align__(16) unsigned h2v[128];      // full h packed

  const unsigned* base = wp3 + (size_t)((dir * 2 + p) * 64) * 1024;
  for (int e = NV; e < 64; ++e)
    wl[j * 28 + (e - NV)] = base[e * 1024 + j];
  unsigned wv[NV];
#pragma unroll
  for (int e = 0; e < NV; ++e) wv[e] = base[e * 1024 + j];

  float exv = extra ? extra[dir * 1024 + R] : 0.f;
  if (j < 128) h2v[j] = 0u;
  float cst = 0.f;
  __syncthreads();

  u64* mypay = pay + (dir * 2 + p) * 128;
  u64* peerpay = pay + (dir * 2 + (1 - p)) * 128;

  const float* xp = xg + dir * 1024;
  const int t0 = dir ? (kT - 1) : 0;
  const int dt = dir ? -1 : 1;
  float xc = xp[(long)t0 * 2048 + R] + exv;

  for (int s = 0; s < kT; ++s) {
    const int t = t0 + s * dt;
    float xn_ = 0.f;
    if (s + 1 < kT) xn_ = xp[(long)(t + dt) * 2048 + R];
    // consume peer's h-half for step s: tagged payload, single RTT per retry
    if (j < 64 && s > 0) {
      u64 v;
      int guard = 0;
      do {
        v = __hip_atomic_load(&peerpay[(s & 1) * 64 + j],
                              __ATOMIC_RELAXED, __HIP_MEMORY_SCOPE_AGENT);
      } while (__any((int)((unsigned)(v >> 32) < (unsigned)s)) && ++guard < (1 << 20));
      h2v[64 * (1 - p) + j] = (unsigned)v;
    }
    __syncthreads();
    // dot over this thread's K-half
    const uint4* h4 = ((const uint4*)h2v) + q * 16;
    float acc = 0.f;
#pragma unroll
    for (int c = 0; c < NV / 4; ++c) {
      uint4 hh = h4[c];
      acc = fdot2u(wv[4 * c + 0], hh.x, acc);
      acc = fdot2u(wv[4 * c + 1], hh.y, acc);
      acc = fdot2u(wv[4 * c + 2], hh.z, acc);
      acc = fdot2u(wv[4 * c + 3], hh.w, acc);
    }
#pragma unroll
    for (int c = 0; c < NL / 4; ++c) {
      uint4 hh = h4[NV / 4 + c];
      uint4 qw = *(const uint4*)&wl[j * 28 + 4 * c];
      acc = fdot2u(qw.x, hh.x, acc);
      acc = fdot2u(qw.y, hh.y, acc);
      acc = fdot2u(qw.z, hh.z, acc);
      acc = fdot2u(qw.w, hh.w, acc);
    }
    float sfull = acc + __shfl_xor(acc, 32);
    float sv = sfull + xc;
    float act = (gate == 2) ? tanh_f(sv) : sigm(sv);
    if (q == 0) gact[r_local] = act;
    __syncthreads();
    if (j < 128) {
      float iv  = gact[j];
      float fv  = gact[128 + j];
      float gv  = gact[256 + j];
      float ovv = gact[384 + j];
      cst = fv * cst + iv * gv;
      float h = ovv * tanh_f(cst);
      out[(long)t * 512 + dir * 256 + 128 * p + j] = h;
      float hx = __shfl_xor(h, 1);
      if (!(j & 1)) {
        int idx = j >> 1;                       // 0..63
        unsigned hp = pack_h2(h, hx);
        h2v[64 * p + idx] = hp;
        u64 tagged = ((u64)(unsigned)(s + 1) << 32) | (u64)hp;
        __hip_atomic_store(&mypay[((s + 1) & 1) * 64 + idx], tagged,
                           __ATOMIC_RELAXED, __HIP_MEMORY_SCOPE_AGENT);
      }
    }
    __syncthreads();
    xc = xn_ + exv;
  }
}

// ---------------- final row softmax ----------------
__global__ __launch_bounds__(256) void softmax_rows(
    const float* __restrict__ logits, float* __restrict__ outp) {
  int t = blockIdx.x, tid = threadIdx.x;
  __shared__ float red[256];
  const float* lr = logits + (long)t * 4096;
  float v[16];
  float mx = -1e30f;
#pragma unroll
  for (int i = 0; i < 16; i++) { v[i] = lr[tid + 256 * i]; mx = fmaxf(mx, v[i]); }
  red[tid] = mx; __syncthreads();
  for (int s = 128; s > 0; s >>= 1) {
    if (tid < s) red[tid] = fmaxf(red[tid], red[tid + s]);
    __syncthreads();
  }
  mx = red[0]; __syncthreads();
  float sm = 0.f;
#pragma unroll
  for (int i = 0; i < 16; i++) { v[i] = __expf(v[i] - mx); sm += v[i]; }
  red[tid] = sm; __syncthreads();
  for (int s = 128; s > 0; s >>= 1) {
    if (tid < s) red[tid] += red[tid + s];
    __syncthreads();
  }
  float rz = 1.f / red[0];
#pragma unroll
  for (int i = 0; i < 16; i++) outp[(long)t * 4096 + tid + 256 * i] = v[i] * rz;
}

// ---------------- launch ----------------
extern "C" void kernel_launch(void* const* d_in, const int* in_sizes, int n_in,
                              void* d_out, int out_size, void* d_ws, size_t ws_size,
                              hipStream_t stream) {
  const float* c        = (const float*)d_in[0];
  const float* memory   = (const float*)d_in[1];
  const float* enc_Wih  = (const float*)d_in[2];
  const float* enc_Whh  = (const float*)d_in[3];
  const float* enc_bih  = (const float*)d_in[4];
  const float* enc_bhh  = (const float*)d_in[5];
  const float* cenc_Wih = (const float*)d_in[6];
  const float* cenc_Whh = (const float*)d_in[7];
  const float* cenc_bih = (const float*)d_in[8];
  const float* cenc_bhh = (const float*)d_in[9];
  const float* know_W   = (const float*)d_in[10];
  const float* know_b   = (const float*)d_in[11];
  const float* l0_Wih   = (const float*)d_in[12];
  const float* l0_Whh   = (const float*)d_in[13];
  const float* l0_bih   = (const float*)d_in[14];
  const float* l0_bhh   = (const float*)d_in[15];
  const float* l1_Wih   = (const float*)d_in[16];
  const float* l1_Whh   = (const float*)d_in[17];
  const float* l1_bih   = (const float*)d_in[18];
  const float* l1_bhh   = (const float*)d_in[19];
  const float* out_W    = (const float*)d_in[20];
  const float* out_b    = (const float*)d_in[21];

  float* ws = (float*)d_ws;
  float* outp = (float*)d_out;

  float* xgg   = ws;                  // 1,572,864   [T][768]
  float* cW    = ws + 1572864;        // 4,194,304   [T][2048]
  float* wcat  = ws + 5767168;        //   786,432
  float* l0out = ws + 6553600;        // 1,048,576   [T][512]
  float* xg1   = ws + 7602176;        // 4,194,304   [T][2048]
  unsigned* wprep3 = (unsigned*)(ws + 11796480);  // 524,288 u32 (2 MB)
  float* bcat  = ws + 12320768;       // 768
  float* bias0 = ws + 12321536;       // 2048
  float* bias1 = ws + 12323584;       // 2048
  float* u_vec = ws + 12325632;       // 256
  float* d_att = ws + 12325888;       // 8192
  float* p_att = ws + 12334080;       // 8192
  float* h_acc = ws + 12342272;       // 256
  float* o_vec = ws + 12342528;       // 1024
  float* ov    = ws + 12343552;       // 2048
  float* l1out = ws + 12345600;       // 1,048,576  (ends 13,394,176)
  unsigned* wgru = (unsigned*)(ws + 13656320);      // 49,152 u32
  u64* payload = (u64*)(ws + 13705472);             // 1024 u64 = 8 KB (2 layers × 512)
  float* logits = ws;                 // 8,388,608   aliases early regions

  prep_kernel<<<512, 256, 0, stream>>>(enc_Wih, enc_bih, cenc_Wih, cenc_bih,
                                       enc_Whh, cenc_Whh,
                                       l0_Whh, l1_Whh, l0_bih, l0_bhh, l1_bih, l1_bhh,
                                       wcat, bcat, bias0, bias1, wprep3, wgru, payload);
  gemm_bt<<<dim3(768 / 64, 2048 / 64), 256, 0, stream>>>(c, wcat, bcat, xgg, 2048, 768, 1024);
  gemm_bt<<<dim3(2048 / 64, 2048 / 64), 256, 0, stream>>>(c, l0_Wih, bias0, cW, 2048, 2048, 1024);
  gru2<<<4, 256, 0, stream>>>(xgg, c, wgru, enc_Wih, enc_bih, enc_bhh,
                              cenc_Wih, cenc_bih, cenc_bhh,
                              u_vec, outp + kOUT_ELEMS);
  attn_dots<<<256, 256, 0, stream>>>(memory, u_vec, d_att);
  attn_soft<<<1, 1024, 0, stream>>>(d_att, p_att, h_acc);
  attn_h<<<64, 256, 0, stream>>>(memory, p_att, h_acc);
  attn_o<<<8, 128, 0, stream>>>(u_vec, h_acc, know_W, know_b, o_vec);
  attn_ov<<<16, 128, 0, stream>>>(o_vec, l0_Wih, ov);
  lstm_cc<<<16, 1024, 0, stream>>>(wprep3, cW, ov, l0out, payload);
  gemm_bt<<<dim3(2048 / 64, 2048 / 64), 256, 0, stream>>>(l0out, l1_Wih, bias1, xg1, 2048, 2048, 512);
  lstm_cc<<<16, 1024, 0, stream>>>(wprep3 + 262144, xg1, nullptr, l1out, payload + 512);
  gemm_bt<<<dim3(4096 / 64, 2048 / 64), 256, 0, stream>>>(l1out, out_W, out_b, logits, 2048, 4096, 512);
  softmax_rows<<<2048, 256, 0, stream>>>(logits, outp);
}

// Round 15
// 7450.067 us; speedup vs baseline: 1.7457x; 1.1152x over previous
//
#include <hip/hip_runtime.h>
#include <hip/hip_bf16.h>

// ---------------- constants ----------------
static constexpr int kT    = 2048;
static constexpr int kOUT_ELEMS = 2048 * 4096;   // output 0 size

typedef _Float16 half2_t __attribute__((ext_vector_type(2)));
typedef unsigned long long u64;

__device__ __forceinline__ unsigned pack_h2(float a, float b) {
  half2_t h{(_Float16)a, (_Float16)b};
  return __builtin_bit_cast(unsigned, h);
}
__device__ __forceinline__ float fdot2u(unsigned a, unsigned b, float c) {
  return __builtin_amdgcn_fdot2(__builtin_bit_cast(half2_t, a),
                                __builtin_bit_cast(half2_t, b), c, false);
}
__device__ __forceinline__ float sigm(float x) {
  return 1.f / (1.f + __expf(-x));
}
__device__ __forceinline__ float tanh_f(float x) {
  float ax = fabsf(x);
  float e = __expf(-2.f * ax);
  float r = (1.f - e) / (1.f + e);
  return x < 0.f ? -r : r;
}

// ---------------- K0: prep ----------------
// wprep4 [ld<4][p<4][e<32][j<1024]: weight half2 e for thread j of block (ld,p).
//   thread j: w=j>>6, l=j&63, qk=l>>4, rowpart=l&15, r_local=w*16+rowpart,
//   gate=r_local>>6, m=r_local&63, R=gate*256+64p+m, half2 col = 32*qk+e
//   (FIX vs R14: was 64*qk+e -> OOB read of W at qk>=2 and weight/h misalignment)
// wgru [g2<2][e<64][row<384]; payload tags zeroed each launch.
__global__ __launch_bounds__(256) void prep_kernel(
    const float* __restrict__ enc_Wih, const float* __restrict__ enc_bih,
    const float* __restrict__ cenc_Wih, const float* __restrict__ cenc_bih,
    const float* __restrict__ enc_Whh, const float* __restrict__ cenc_Whh,
    const float* __restrict__ l0_Whh, const float* __restrict__ l1_Whh,
    const float* __restrict__ l0_bih, const float* __restrict__ l0_bhh,
    const float* __restrict__ l1_bih, const float* __restrict__ l1_bhh,
    float* __restrict__ wcat, float* __restrict__ bcat,
    float* __restrict__ bias0, float* __restrict__ bias1,
    unsigned* __restrict__ wprep4, unsigned* __restrict__ wgru,
    u64* __restrict__ payz) {
  int idx0 = blockIdx.x * blockDim.x + threadIdx.x;
  int stride = gridDim.x * blockDim.x;
  for (int i = idx0; i < 1024; i += stride) payz[i] = 0ull;   // re-zero every launch
  for (int i = idx0; i < 768 * 1024; i += stride) {
    int r = i >> 10, cc = i & 1023;
    wcat[i] = (r < 384) ? enc_Wih[r * 1024 + cc] : cenc_Wih[(r - 384) * 1024 + cc];
  }
  for (int i = idx0; i < 768; i += stride)
    bcat[i] = (i < 384) ? enc_bih[i] : cenc_bih[i - 384];
  for (int i = idx0; i < 2048; i += stride) {
    bias0[i] = l0_bih[i] + l0_bhh[i];
    bias1[i] = l1_bih[i] + l1_bhh[i];
  }
  for (int i = idx0; i < 4 * 4 * 32 * 1024; i += stride) {
    int j = i & 1023;
    int e = (i >> 10) & 31;
    int p = (i >> 15) & 3;
    int ld = i >> 17;  // layer*2 + dir
    const float* W = (ld < 2 ? l0_Whh : l1_Whh) + (ld & 1) * 1024 * 256;
    int w = j >> 6, l = j & 63;
    int qk = l >> 4, rowpart = l & 15;
    int r_local = w * 16 + rowpart;
    int gate = r_local >> 6, m = r_local & 63;
    int R = gate * 256 + 64 * p + m;
    int col = 2 * (32 * qk + e);          // <- FIXED (was 64*qk+e)
    wprep4[i] = pack_h2(W[R * 256 + col], W[R * 256 + col + 1]);
  }
  for (int i = idx0; i < 2 * 64 * 384; i += stride) {
    int row = i % 384;
    int e = (i / 384) & 63;
    int g2 = i / (64 * 384);
    const float* W = g2 ? cenc_Whh : enc_Whh;   // dir0 at base
    wgru[i] = pack_h2(W[row * 128 + 2 * e], W[row * 128 + 2 * e + 1]);
  }
}

// ---------------- fp32 tiled GEMM: C[M][N] = A[M][K] * B[N][K]^T + bias[N] ----------------
__global__ __launch_bounds__(256) void gemm_bt(
    const float* __restrict__ A, const float* __restrict__ B,
    const float* __restrict__ bias, float* __restrict__ C,
    int M, int N, int K) {
  __shared__ float As[16][68];
  __shared__ float Bs[16][68];
  int tid = threadIdx.x;
  int tx = tid & 15, ty = tid >> 4;
  int m0 = blockIdx.y * 64, n0 = blockIdx.x * 64;
  int lr = tid >> 2;
  int lc = (tid & 3) << 2;
  float acc[4][4] = {};
  const float* Ap = A + (long)(m0 + lr) * K + lc;
  const float* Bp = B + (long)(n0 + lr) * K + lc;
  for (int k0 = 0; k0 < K; k0 += 16) {
    float4 a4 = *(const float4*)(Ap + k0);
    float4 b4 = *(const float4*)(Bp + k0);
    __syncthreads();
    As[lc + 0][lr] = a4.x; As[lc + 1][lr] = a4.y; As[lc + 2][lr] = a4.z; As[lc + 3][lr] = a4.w;
    Bs[lc + 0][lr] = b4.x; Bs[lc + 1][lr] = b4.y; Bs[lc + 2][lr] = b4.z; Bs[lc + 3][lr] = b4.w;
    __syncthreads();
#pragma unroll
    for (int kk = 0; kk < 16; kk++) {
      float4 ra = *(const float4*)&As[kk][ty << 2];
      float4 rb = *(const float4*)&Bs[kk][tx << 2];
      float av[4] = {ra.x, ra.y, ra.z, ra.w};
      float bv[4] = {rb.x, rb.y, rb.z, rb.w};
#pragma unroll
      for (int i = 0; i < 4; i++)
#pragma unroll
        for (int jj = 0; jj < 4; jj++)
          acc[i][jj] += av[i] * bv[jj];
    }
  }
#pragma unroll
  for (int i = 0; i < 4; i++) {
    int m = m0 + (ty << 2) + i;
#pragma unroll
    for (int jj = 0; jj < 4; jj++) {
      int n = n0 + (tx << 2) + jj;
      C[(long)m * N + n] = acc[i][jj] + (bias ? bias[n] : 0.f);
    }
  }
}

// ---------------- GRU: 256 threads, fp16 weights fully VGPR-resident ----------------
__global__ __launch_bounds__(256) void gru2(
    const float* __restrict__ xgg,   // [T][768]
    const float* __restrict__ c_in,  // [T][1024]
    const unsigned* __restrict__ wgru,
    const float* __restrict__ enc_Wih, const float* __restrict__ enc_bih,
    const float* __restrict__ enc_bhh,
    const float* __restrict__ cenc_Wih, const float* __restrict__ cenc_bih,
    const float* __restrict__ cenc_bhh,
    float* __restrict__ u_out, float* __restrict__ cmem_out) {
  int b = blockIdx.x, j = threadIdx.x;
  __shared__ __align__(16) unsigned h2g[64];
  __shared__ float zs[128];
  const bool dual = j < 128;
  if (b < 2) {
    const unsigned* wg = wgru + b * (64 * 384);
    const float* bhh = b ? cenc_bhh : enc_bhh;
    unsigned w0[64], w1[64];
#pragma unroll
    for (int e = 0; e < 64; ++e) w0[e] = wg[e * 384 + j];
    float bh0 = bhh[j], bh1 = 0.f;
    if (dual) {
#pragma unroll
      for (int e = 0; e < 64; ++e) w1[e] = wg[e * 384 + 256 + j];
      bh1 = bhh[256 + j];
    }
    if (j < 64) h2g[j] = 0u;
    float hreg = 0.f;
    __syncthreads();
    const float* xp = xgg + b * 384;
    float x0 = xp[j];
    float x1 = dual ? xp[256 + j] : 0.f;
    for (int t = 0; t < kT; ++t) {
      float x0n = 0.f, x1n = 0.f;
      if (t + 1 < kT) {
        x0n = xp[(t + 1) * 768 + j];
        if (dual) x1n = xp[(t + 1) * 768 + 256 + j];
      }
      const uint4* h4 = (const uint4*)h2g;
      float a0 = 0.f, a1 = 0.f;
#pragma unroll
      for (int k = 0; k < 16; ++k) {
        uint4 hh = h4[k];
        a0 = fdot2u(w0[4 * k + 0], hh.x, a0);
        a0 = fdot2u(w0[4 * k + 1], hh.y, a0);
        a0 = fdot2u(w0[4 * k + 2], hh.z, a0);
        a0 = fdot2u(w0[4 * k + 3], hh.w, a0);
        if (dual) {
          a1 = fdot2u(w1[4 * k + 0], hh.x, a1);
          a1 = fdot2u(w1[4 * k + 1], hh.y, a1);
          a1 = fdot2u(w1[4 * k + 2], hh.z, a1);
          a1 = fdot2u(w1[4 * k + 3], hh.w, a1);
        }
      }
      if (!dual) zs[j - 128] = sigm(x0 + a0 + bh0);
      __syncthreads();
      if (dual) {
        float r = sigm(x0 + a0 + bh0);
        float n = tanh_f(x1 + r * (a1 + bh1));
        float z = zs[j];
        hreg = (1.f - z) * n + z * hreg;
        float hx = __shfl_xor(hreg, 1);
        if (!(j & 1)) h2g[j >> 1] = pack_h2(hreg, hx);
      }
      __syncthreads();
      x0 = x0n; x1 = x1n;
    }
    if (dual) { if (b == 0) u_out[j] = hreg; else cmem_out[j] = hreg; }
  } else {
    const float* Wih = ((b == 2) ? enc_Wih : cenc_Wih) + 384 * 1024;
    const float* bih = ((b == 2) ? enc_bih : cenc_bih) + 384;
    const float* bhh = ((b == 2) ? enc_bhh : cenc_bhh) + 384;
    const float* crow = c_in + (long)(kT - 1) * 1024;
    float a0 = bih[j], a1 = 0.f;
    {
      const float* wr = Wih + (long)j * 1024;
      for (int k = 0; k < 1024; k += 4) {
        float4 cv = *(const float4*)&crow[k];
        float4 wv = *(const float4*)&wr[k];
        a0 += cv.x * wv.x + cv.y * wv.y + cv.z * wv.z + cv.w * wv.w;
      }
    }
    if (dual) {
      a1 = bih[256 + j];
      const float* wr = Wih + (long)(256 + j) * 1024;
      for (int k = 0; k < 1024; k += 4) {
        float4 cv = *(const float4*)&crow[k];
        float4 wv = *(const float4*)&wr[k];
        a1 += cv.x * wv.x + cv.y * wv.y + cv.z * wv.z + cv.w * wv.w;
      }
    }
    if (!dual) zs[j - 128] = sigm(a0 + bhh[j]);
    __syncthreads();
    if (dual) {
      float r = sigm(a0 + bhh[j]);
      float n = tanh_f(a1 + r * bhh[256 + j]);
      float z = zs[j];
      float h = (1.f - z) * n;
      if (b == 2) u_out[128 + j] = h; else cmem_out[128 + j] = h;
    }
  }
}

// ---------------- attention ----------------
__global__ __launch_bounds__(256) void attn_dots(
    const float* __restrict__ mem, const float* __restrict__ u, float* __restrict__ d) {
  __shared__ float us[256];
  int tid = threadIdx.x;
  us[tid] = u[tid];
  __syncthreads();
  int g = tid >> 3, l8 = tid & 7;
  int row = blockIdx.x * 32 + g;
  const float* mr = mem + (long)row * 256 + l8 * 32;
  float p = 0.f;
#pragma unroll
  for (int k = 0; k < 32; k += 4) {
    float4 m4 = *(const float4*)&mr[k];
    p += m4.x * us[l8 * 32 + k] + m4.y * us[l8 * 32 + k + 1] +
         m4.z * us[l8 * 32 + k + 2] + m4.w * us[l8 * 32 + k + 3];
  }
  p += __shfl_down(p, 4);
  p += __shfl_down(p, 2);
  p += __shfl_down(p, 1);
  if (l8 == 0) d[row] = p;
}

__global__ __launch_bounds__(1024) void attn_soft(
    const float* __restrict__ d, float* __restrict__ p, float* __restrict__ h_acc) {
  __shared__ float red[1024];
  int tid = threadIdx.x;
  float v[8];
  float mx = -1e30f;
#pragma unroll
  for (int i = 0; i < 8; i++) { v[i] = d[tid * 8 + i]; mx = fmaxf(mx, v[i]); }
  red[tid] = mx; __syncthreads();
  for (int s = 512; s > 0; s >>= 1) {
    if (tid < s) red[tid] = fmaxf(red[tid], red[tid + s]);
    __syncthreads();
  }
  mx = red[0]; __syncthreads();
  float sm = 0.f; float e[8];
#pragma unroll
  for (int i = 0; i < 8; i++) { e[i] = __expf(v[i] - mx); sm += e[i]; }
  red[tid] = sm; __syncthreads();
  for (int s = 512; s > 0; s >>= 1) {
    if (tid < s) red[tid] += red[tid + s];
    __syncthreads();
  }
  float rz = 1.f / red[0];
#pragma unroll
  for (int i = 0; i < 8; i++) p[tid * 8 + i] = e[i] * rz;
  if (tid < 256) h_acc[tid] = 0.f;
}

__global__ __launch_bounds__(256) void attn_h(
    const float* __restrict__ mem, const float* __restrict__ p, float* __restrict__ h_acc) {
  int tid = threadIdx.x;
  int r0 = blockIdx.x * 128;
  float acc = 0.f;
  for (int i = 0; i < 128; i++) acc += p[r0 + i] * mem[(long)(r0 + i) * 256 + tid];
  atomicAdd(&h_acc[tid], acc);
}

__global__ __launch_bounds__(128) void attn_o(
    const float* __restrict__ u, const float* __restrict__ h_acc,
    const float* __restrict__ know_W, const float* __restrict__ know_b,
    float* __restrict__ o) {
  __shared__ float uh[256];
  int tid = threadIdx.x;
  uh[tid] = u[tid] + h_acc[tid];
  uh[128 + tid] = u[128 + tid] + h_acc[128 + tid];
  __syncthreads();
  int row = blockIdx.x * 128 + tid;
  float acc = know_b[row];
  for (int k = 0; k < 256; k += 4) {
    float4 w4 = *(const float4*)&know_W[row * 256 + k];
    acc += w4.x * uh[k] + w4.y * uh[k + 1] + w4.z * uh[k + 2] + w4.w * uh[k + 3];
  }
  o[row] = acc;
}

__global__ __launch_bounds__(128) void attn_ov(
    const float* __restrict__ o, const float* __restrict__ Wih0, float* __restrict__ ov) {
  int row = blockIdx.x * 128 + threadIdx.x;
  float acc = 0.f;
  for (int k = 0; k < 1024; k += 4) {
    float4 w4 = *(const float4*)&Wih0[(long)row * 1024 + k];
    float4 o4 = *(const float4*)&o[k];
    acc += w4.x * o4.x + w4.y * o4.y + w4.z * o4.z + w4.w * o4.w;
  }
  ov[row] = acc;
}

// ---------------- LSTM v15: 4 CUs/direction, all weights in VGPRs ----------------
// grid = 32; active: bid&7 in {0,1}. dir = bid&7, p = bid>>3 (0..3). All 4 blocks of
// a direction land on one XCD (bid%8 round-robin). Block owns h-elems [64p,64p+64)
// = 256 gate rows; thread = (row, K-quarter): 32 half2 weights ALL in VGPR
// (half2 cols [32qk, 32qk+32)). Quarter partials via shfl_xor(16/32).
// h-exchange: tagged u64 payload (tag=s+1 travels with data), slot parity,
// per-lane spin, 3 peers x 32 u64. Max skew 1 step -> distance-2 overwrite safe.
__global__ __launch_bounds__(1024) void lstm_cc4(
    const unsigned* __restrict__ wp4,    // layer base: [dir<2][p<4][e<32][j<1024]
    const float* __restrict__ xg,        // [T][2048] (biases folded)
    const float* __restrict__ extra,     // [2048] rank-1 add or nullptr
    float* __restrict__ out,             // [T][512]
    u64* __restrict__ pay) {             // layer base: [dir*4+p][slot<2][32] u64
  const int bid = blockIdx.x;
  const int xs = bid & 7;
  if (xs >= 2) return;                   // inactive filler blocks
  const int dir = xs, p = bid >> 3;      // p in [0,4)
  const int j = threadIdx.x;
  const int l = j & 63, w = j >> 6;
  const int qk = l >> 4, rowpart = l & 15;
  const int r_local = w * 16 + rowpart;            // [0,256)
  const int gate = r_local >> 6;
  const int m = r_local & 63;
  const int R = gate * 256 + 64 * p + m;           // global gate row

  __shared__ __align__(16) unsigned h2v[128];      // full h packed (h2)
  __shared__ float gact[256];

  const unsigned* base = wp4 + (size_t)dir * 131072 + (size_t)p * 32768;
  unsigned wv[32];
#pragma unroll
  for (int e = 0; e < 32; ++e) wv[e] = base[e * 1024 + j];

  float exv = extra ? extra[dir * 1024 + R] : 0.f;
  if (j < 128) h2v[j] = 0u;
  float cst = 0.f;
  __syncthreads();

  const int bi = dir * 4 + p;
  u64* mypay = pay + bi * 64;
  // consuming lanes j<96: pi = j>>5 (0..2), peer p' = pi + (pi>=p)
  const int pi = (j < 96) ? (j >> 5) : 0;
  const int pp = pi + (pi >= p ? 1 : 0);
  u64* peerpay = pay + (dir * 4 + pp) * 64;
  const int pidx = j & 31;

  const float* xp = xg + dir * 1024;
  const int t0 = dir ? (kT - 1) : 0;
  const int dt = dir ? -1 : 1;
  float xc = xp[(long)t0 * 2048 + R] + exv;

  for (int s = 0; s < kT; ++s) {
    const int t = t0 + s * dt;
    float xn_ = 0.f;
    if (s + 1 < kT) xn_ = xp[(long)(t + dt) * 2048 + R];
    // consume 3 peers' h-quarters for step s (tag >= s), per-lane spin
    if (j < 96 && s > 0) {
      u64 v;
      int guard = 0;
      do {
        v = __hip_atomic_load(&peerpay[(s & 1) * 32 + pidx],
                              __ATOMIC_RELAXED, __HIP_MEMORY_SCOPE_AGENT);
      } while ((unsigned)(v >> 32) < (unsigned)s && ++guard < (1 << 18));
      h2v[32 * pp + pidx] = (unsigned)v;
    }
    __syncthreads();   // h2v complete (own quarter written end of prev step)
    // dot over this thread's K-quarter: h2 elems [32qk, 32qk+32)
    const uint4* h4 = ((const uint4*)h2v) + qk * 8;
    float acc = 0.f;
#pragma unroll
    for (int c = 0; c < 8; ++c) {
      uint4 hh = h4[c];
      acc = fdot2u(wv[4 * c + 0], hh.x, acc);
      acc = fdot2u(wv[4 * c + 1], hh.y, acc);
      acc = fdot2u(wv[4 * c + 2], hh.z, acc);
      acc = fdot2u(wv[4 * c + 3], hh.w, acc);
    }
    acc += __shfl_xor(acc, 16);
    acc += __shfl_xor(acc, 32);
    float sv = acc + xc;
    float act = (gate == 2) ? tanh_f(sv) : sigm(sv);
    if (qk == 0) gact[r_local] = act;
    __syncthreads();   // gact ready; all h2v reads done
    if (j < 64) {
      float iv  = gact[j];
      float fv  = gact[64 + j];
      float gv  = gact[128 + j];
      float ovv = gact[192 + j];
      cst = fv * cst + iv * gv;
      float h = ovv * tanh_f(cst);
      out[(long)t * 512 + dir * 256 + 64 * p + j] = h;
      float hx = __shfl_xor(h, 1);
      if (!(j & 1)) {
        int idx = j >> 1;                       // 0..31
        unsigned hp = pack_h2(h, hx);
        h2v[32 * p + idx] = hp;                 // own quarter for next step
        u64 tagged = ((u64)(unsigned)(s + 1) << 32) | (u64)hp;
        __hip_atomic_store(&mypay[((s + 1) & 1) * 32 + idx], tagged,
                           __ATOMIC_RELAXED, __HIP_MEMORY_SCOPE_AGENT);
      }
    }
    // no barrier needed: next consume writes disjoint h2v entries; next barrier orders
    xc = xn_ + exv;
  }
}

// ---------------- final row softmax ----------------
__global__ __launch_bounds__(256) void softmax_rows(
    const float* __restrict__ logits, float* __restrict__ outp) {
  int t = blockIdx.x, tid = threadIdx.x;
  __shared__ float red[256];
  const float* lr = logits + (long)t * 4096;
  float v[16];
  float mx = -1e30f;
#pragma unroll
  for (int i = 0; i < 16; i++) { v[i] = lr[tid + 256 * i]; mx = fmaxf(mx, v[i]); }
  red[tid] = mx; __syncthreads();
  for (int s = 128; s > 0; s >>= 1) {
    if (tid < s) red[tid] = fmaxf(red[tid], red[tid + s]);
    __syncthreads();
  }
  mx = red[0]; __syncthreads();
  float sm = 0.f;
#pragma unroll
  for (int i = 0; i < 16; i++) { v[i] = __expf(v[i] - mx); sm += v[i]; }
  red[tid] = sm; __syncthreads();
  for (int s = 128; s > 0; s >>= 1) {
    if (tid < s) red[tid] += red[tid + s];
    __syncthreads();
  }
  float rz = 1.f / red[0];
#pragma unroll
  for (int i = 0; i < 16; i++) outp[(long)t * 4096 + tid + 256 * i] = v[i] * rz;
}

// ---------------- launch ----------------
extern "C" void kernel_launch(void* const* d_in, const int* in_sizes, int n_in,
                              void* d_out, int out_size, void* d_ws, size_t ws_size,
                              hipStream_t stream) {
  const float* c        = (const float*)d_in[0];
  const float* memory   = (const float*)d_in[1];
  const float* enc_Wih  = (const float*)d_in[2];
  const float* enc_Whh  = (const float*)d_in[3];
  const float* enc_bih  = (const float*)d_in[4];
  const float* enc_bhh  = (const float*)d_in[5];
  const float* cenc_Wih = (const float*)d_in[6];
  const float* cenc_Whh = (const float*)d_in[7];
  const float* cenc_bih = (const float*)d_in[8];
  const float* cenc_bhh = (const float*)d_in[9];
  const float* know_W   = (const float*)d_in[10];
  const float* know_b   = (const float*)d_in[11];
  const float* l0_Wih   = (const float*)d_in[12];
  const float* l0_Whh   = (const float*)d_in[13];
  const float* l0_bih   = (const float*)d_in[14];
  const float* l0_bhh   = (const float*)d_in[15];
  const float* l1_Wih   = (const float*)d_in[16];
  const float* l1_Whh   = (const float*)d_in[17];
  const float* l1_bih   = (const float*)d_in[18];
  const float* l1_bhh   = (const float*)d_in[19];
  const float* out_W    = (const float*)d_in[20];
  const float* out_b    = (const float*)d_in[21];

  float* ws = (float*)d_ws;
  float* outp = (float*)d_out;

  float* xgg   = ws;                  // 1,572,864   [T][768]
  float* cW    = ws + 1572864;        // 4,194,304   [T][2048]
  float* wcat  = ws + 5767168;        //   786,432
  float* l0out = ws + 6553600;        // 1,048,576   [T][512]
  float* xg1   = ws + 7602176;        // 4,194,304   [T][2048]
  unsigned* wprep4 = (unsigned*)(ws + 11796480);  // 524,288 u32 (2 MB)
  float* bcat  = ws + 12320768;       // 768
  float* bias0 = ws + 12321536;       // 2048
  float* bias1 = ws + 12323584;       // 2048
  float* u_vec = ws + 12325632;       // 256
  float* d_att = ws + 12325888;       // 8192
  float* p_att = ws + 12334080;       // 8192
  float* h_acc = ws + 12342272;       // 256
  float* o_vec = ws + 12342528;       // 1024
  float* ov    = ws + 12343552;       // 2048
  float* l1out = ws + 12345600;       // 1,048,576  (ends 13,394,176)
  unsigned* wgru = (unsigned*)(ws + 13656320);      // 49,152 u32
  u64* payload = (u64*)(ws + 13705472);             // 1024 u64 (2 layers × 8 blk × 64)
  float* logits = ws;                 // 8,388,608   aliases early regions

  prep_kernel<<<512, 256, 0, stream>>>(enc_Wih, enc_bih, cenc_Wih, cenc_bih,
                                       enc_Whh, cenc_Whh,
                                       l0_Whh, l1_Whh, l0_bih, l0_bhh, l1_bih, l1_bhh,
                                       wcat, bcat, bias0, bias1, wprep4, wgru, payload);
  gemm_bt<<<dim3(768 / 64, 2048 / 64), 256, 0, stream>>>(c, wcat, bcat, xgg, 2048, 768, 1024);
  gemm_bt<<<dim3(2048 / 64, 2048 / 64), 256, 0, stream>>>(c, l0_Wih, bias0, cW, 2048, 2048, 1024);
  gru2<<<4, 256, 0, stream>>>(xgg, c, wgru, enc_Wih, enc_bih, enc_bhh,
                              cenc_Wih, cenc_bih, cenc_bhh,
                              u_vec, outp + kOUT_ELEMS);
  attn_dots<<<256, 256, 0, stream>>>(memory, u_vec, d_att);
  attn_soft<<<1, 1024, 0, stream>>>(d_att, p_att, h_acc);
  attn_h<<<64, 256, 0, stream>>>(memory, p_att, h_acc);
  attn_o<<<8, 128, 0, stream>>>(u_vec, h_acc, know_W, know_b, o_vec);
  attn_ov<<<16, 128, 0, stream>>>(o_vec, l0_Wih, ov);
  lstm_cc4<<<32, 1024, 0, stream>>>(wprep4, cW, ov, l0out, payload);
  gemm_bt<<<dim3(2048 / 64, 2048 / 64), 256, 0, stream>>>(l0out, l1_Wih, bias1, xg1, 2048, 2048, 512);
  lstm_cc4<<<32, 1024, 0, stream>>>(wprep4 + 262144, xg1, nullptr, l1out, payload + 512);
  gemm_bt<<<dim3(4096 / 64, 2048 / 64), 256, 0, stream>>>(l1out, out_W, out_b, logits, 2048, 4096, 512);
  softmax_rows<<<2048, 256, 0, stream>>>(logits, outp);
}

// Round 16
// 7399.738 us; speedup vs baseline: 1.7576x; 1.0068x over previous
//
#include <hip/hip_runtime.h>
#include <hip/hip_bf16.h>

// ---------------- constants ----------------
static constexpr int kT    = 2048;
static constexpr int kOUT_ELEMS = 2048 * 4096;   // output 0 size

typedef _Float16 half2_t __attribute__((ext_vector_type(2)));
typedef unsigned long long u64;

__device__ __forceinline__ unsigned pack_h2(float a, float b) {
  half2_t h{(_Float16)a, (_Float16)b};
  return __builtin_bit_cast(unsigned, h);
}
__device__ __forceinline__ float fdot2u(unsigned a, unsigned b, float c) {
  return __builtin_amdgcn_fdot2(__builtin_bit_cast(half2_t, a),
                                __builtin_bit_cast(half2_t, b), c, false);
}
__device__ __forceinline__ float sigm(float x) {
  return 1.f / (1.f + __expf(-x));
}
__device__ __forceinline__ float tanh_f(float x) {
  float ax = fabsf(x);
  float e = __expf(-2.f * ax);
  float r = (1.f - e) / (1.f + e);
  return x < 0.f ? -r : r;
}

// ---------------- K0: prep ----------------
// wprep5 [ld<4][p<4][e<128][j<256]: half2 col e of row R for thread j of block (ld,p);
//   gate=j>>6, m=j&63, R=gate*256+64p+m, col=2e. (per ld: 131072 u32)
// wgru [g2<2][e<64][row<384]; payload tags zeroed each launch.
__global__ __launch_bounds__(256) void prep_kernel(
    const float* __restrict__ enc_Wih, const float* __restrict__ enc_bih,
    const float* __restrict__ cenc_Wih, const float* __restrict__ cenc_bih,
    const float* __restrict__ enc_Whh, const float* __restrict__ cenc_Whh,
    const float* __restrict__ l0_Whh, const float* __restrict__ l1_Whh,
    const float* __restrict__ l0_bih, const float* __restrict__ l0_bhh,
    const float* __restrict__ l1_bih, const float* __restrict__ l1_bhh,
    float* __restrict__ wcat, float* __restrict__ bcat,
    float* __restrict__ bias0, float* __restrict__ bias1,
    unsigned* __restrict__ wprep5, unsigned* __restrict__ wgru,
    u64* __restrict__ payz) {
  int idx0 = blockIdx.x * blockDim.x + threadIdx.x;
  int stride = gridDim.x * blockDim.x;
  for (int i = idx0; i < 1024; i += stride) payz[i] = 0ull;   // re-zero every launch
  for (int i = idx0; i < 768 * 1024; i += stride) {
    int r = i >> 10, cc = i & 1023;
    wcat[i] = (r < 384) ? enc_Wih[r * 1024 + cc] : cenc_Wih[(r - 384) * 1024 + cc];
  }
  for (int i = idx0; i < 768; i += stride)
    bcat[i] = (i < 384) ? enc_bih[i] : cenc_bih[i - 384];
  for (int i = idx0; i < 2048; i += stride) {
    bias0[i] = l0_bih[i] + l0_bhh[i];
    bias1[i] = l1_bih[i] + l1_bhh[i];
  }
  for (int i = idx0; i < 4 * 4 * 128 * 256; i += stride) {
    int j = i & 255;
    int e = (i >> 8) & 127;
    int p = (i >> 15) & 3;
    int ld = i >> 17;  // layer*2 + dir
    const float* W = (ld < 2 ? l0_Whh : l1_Whh) + (ld & 1) * 1024 * 256;
    int gate = j >> 6, m = j & 63;
    int R = gate * 256 + 64 * p + m;
    wprep5[i] = pack_h2(W[R * 256 + 2 * e], W[R * 256 + 2 * e + 1]);
  }
  for (int i = idx0; i < 2 * 64 * 384; i += stride) {
    int row = i % 384;
    int e = (i / 384) & 63;
    int g2 = i / (64 * 384);
    const float* W = g2 ? cenc_Whh : enc_Whh;   // dir0 at base
    wgru[i] = pack_h2(W[row * 128 + 2 * e], W[row * 128 + 2 * e + 1]);
  }
}

// ---------------- fp32 tiled GEMM: C[M][N] = A[M][K] * B[N][K]^T + bias[N] ----------------
__global__ __launch_bounds__(256) void gemm_bt(
    const float* __restrict__ A, const float* __restrict__ B,
    const float* __restrict__ bias, float* __restrict__ C,
    int M, int N, int K) {
  __shared__ float As[16][68];
  __shared__ float Bs[16][68];
  int tid = threadIdx.x;
  int tx = tid & 15, ty = tid >> 4;
  int m0 = blockIdx.y * 64, n0 = blockIdx.x * 64;
  int lr = tid >> 2;
  int lc = (tid & 3) << 2;
  float acc[4][4] = {};
  const float* Ap = A + (long)(m0 + lr) * K + lc;
  const float* Bp = B + (long)(n0 + lr) * K + lc;
  for (int k0 = 0; k0 < K; k0 += 16) {
    float4 a4 = *(const float4*)(Ap + k0);
    float4 b4 = *(const float4*)(Bp + k0);
    __syncthreads();
    As[lc + 0][lr] = a4.x; As[lc + 1][lr] = a4.y; As[lc + 2][lr] = a4.z; As[lc + 3][lr] = a4.w;
    Bs[lc + 0][lr] = b4.x; Bs[lc + 1][lr] = b4.y; Bs[lc + 2][lr] = b4.z; Bs[lc + 3][lr] = b4.w;
    __syncthreads();
#pragma unroll
    for (int kk = 0; kk < 16; kk++) {
      float4 ra = *(const float4*)&As[kk][ty << 2];
      float4 rb = *(const float4*)&Bs[kk][tx << 2];
      float av[4] = {ra.x, ra.y, ra.z, ra.w};
      float bv[4] = {rb.x, rb.y, rb.z, rb.w};
#pragma unroll
      for (int i = 0; i < 4; i++)
#pragma unroll
        for (int jj = 0; jj < 4; jj++)
          acc[i][jj] += av[i] * bv[jj];
    }
  }
#pragma unroll
  for (int i = 0; i < 4; i++) {
    int m = m0 + (ty << 2) + i;
#pragma unroll
    for (int jj = 0; jj < 4; jj++) {
      int n = n0 + (tx << 2) + jj;
      C[(long)m * N + n] = acc[i][jj] + (bias ? bias[n] : 0.f);
    }
  }
}

// ---------------- GRU: 256 threads, fp16 weights fully VGPR-resident ----------------
__global__ __launch_bounds__(256) void gru2(
    const float* __restrict__ xgg,   // [T][768]
    const float* __restrict__ c_in,  // [T][1024]
    const unsigned* __restrict__ wgru,
    const float* __restrict__ enc_Wih, const float* __restrict__ enc_bih,
    const float* __restrict__ enc_bhh,
    const float* __restrict__ cenc_Wih, const float* __restrict__ cenc_bih,
    const float* __restrict__ cenc_bhh,
    float* __restrict__ u_out, float* __restrict__ cmem_out) {
  int b = blockIdx.x, j = threadIdx.x;
  __shared__ __align__(16) unsigned h2g[64];
  __shared__ float zs[128];
  const bool dual = j < 128;
  if (b < 2) {
    const unsigned* wg = wgru + b * (64 * 384);
    const float* bhh = b ? cenc_bhh : enc_bhh;
    unsigned w0[64], w1[64];
#pragma unroll
    for (int e = 0; e < 64; ++e) w0[e] = wg[e * 384 + j];
    float bh0 = bhh[j], bh1 = 0.f;
    if (dual) {
#pragma unroll
      for (int e = 0; e < 64; ++e) w1[e] = wg[e * 384 + 256 + j];
      bh1 = bhh[256 + j];
    }
    if (j < 64) h2g[j] = 0u;
    float hreg = 0.f;
    __syncthreads();
    const float* xp = xgg + b * 384;
    float x0 = xp[j];
    float x1 = dual ? xp[256 + j] : 0.f;
    for (int t = 0; t < kT; ++t) {
      float x0n = 0.f, x1n = 0.f;
      if (t + 1 < kT) {
        x0n = xp[(t + 1) * 768 + j];
        if (dual) x1n = xp[(t + 1) * 768 + 256 + j];
      }
      const uint4* h4 = (const uint4*)h2g;
      float a0 = 0.f, a1 = 0.f;
#pragma unroll
      for (int k = 0; k < 16; ++k) {
        uint4 hh = h4[k];
        a0 = fdot2u(w0[4 * k + 0], hh.x, a0);
        a0 = fdot2u(w0[4 * k + 1], hh.y, a0);
        a0 = fdot2u(w0[4 * k + 2], hh.z, a0);
        a0 = fdot2u(w0[4 * k + 3], hh.w, a0);
        if (dual) {
          a1 = fdot2u(w1[4 * k + 0], hh.x, a1);
          a1 = fdot2u(w1[4 * k + 1], hh.y, a1);
          a1 = fdot2u(w1[4 * k + 2], hh.z, a1);
          a1 = fdot2u(w1[4 * k + 3], hh.w, a1);
        }
      }
      if (!dual) zs[j - 128] = sigm(x0 + a0 + bh0);
      __syncthreads();
      if (dual) {
        float r = sigm(x0 + a0 + bh0);
        float n = tanh_f(x1 + r * (a1 + bh1));
        float z = zs[j];
        hreg = (1.f - z) * n + z * hreg;
        float hx = __shfl_xor(hreg, 1);
        if (!(j & 1)) h2g[j >> 1] = pack_h2(hreg, hx);
      }
      __syncthreads();
      x0 = x0n; x1 = x1n;
    }
    if (dual) { if (b == 0) u_out[j] = hreg; else cmem_out[j] = hreg; }
  } else {
    const float* Wih = ((b == 2) ? enc_Wih : cenc_Wih) + 384 * 1024;
    const float* bih = ((b == 2) ? enc_bih : cenc_bih) + 384;
    const float* bhh = ((b == 2) ? enc_bhh : cenc_bhh) + 384;
    const float* crow = c_in + (long)(kT - 1) * 1024;
    float a0 = bih[j], a1 = 0.f;
    {
      const float* wr = Wih + (long)j * 1024;
      for (int k = 0; k < 1024; k += 4) {
        float4 cv = *(const float4*)&crow[k];
        float4 wv = *(const float4*)&wr[k];
        a0 += cv.x * wv.x + cv.y * wv.y + cv.z * wv.z + cv.w * wv.w;
      }
    }
    if (dual) {
      a1 = bih[256 + j];
      const float* wr = Wih + (long)(256 + j) * 1024;
      for (int k = 0; k < 1024; k += 4) {
        float4 cv = *(const float4*)&crow[k];
        float4 wv = *(const float4*)&wr[k];
        a1 += cv.x * wv.x + cv.y * wv.y + cv.z * wv.z + cv.w * wv.w;
      }
    }
    if (!dual) zs[j - 128] = sigm(a0 + bhh[j]);
    __syncthreads();
    if (dual) {
      float r = sigm(a0 + bhh[j]);
      float n = tanh_f(a1 + r * bhh[256 + j]);
      float z = zs[j];
      float h = (1.f - z) * n;
      if (b == 2) u_out[128 + j] = h; else cmem_out[128 + j] = h;
    }
  }
}

// ---------------- attention ----------------
__global__ __launch_bounds__(256) void attn_dots(
    const float* __restrict__ mem, const float* __restrict__ u, float* __restrict__ d) {
  __shared__ float us[256];
  int tid = threadIdx.x;
  us[tid] = u[tid];
  __syncthreads();
  int g = tid >> 3, l8 = tid & 7;
  int row = blockIdx.x * 32 + g;
  const float* mr = mem + (long)row * 256 + l8 * 32;
  float p = 0.f;
#pragma unroll
  for (int k = 0; k < 32; k += 4) {
    float4 m4 = *(const float4*)&mr[k];
    p += m4.x * us[l8 * 32 + k] + m4.y * us[l8 * 32 + k + 1] +
         m4.z * us[l8 * 32 + k + 2] + m4.w * us[l8 * 32 + k + 3];
  }
  p += __shfl_down(p, 4);
  p += __shfl_down(p, 2);
  p += __shfl_down(p, 1);
  if (l8 == 0) d[row] = p;
}

__global__ __launch_bounds__(1024) void attn_soft(
    const float* __restrict__ d, float* __restrict__ p, float* __restrict__ h_acc) {
  __shared__ float red[1024];
  int tid = threadIdx.x;
  float v[8];
  float mx = -1e30f;
#pragma unroll
  for (int i = 0; i < 8; i++) { v[i] = d[tid * 8 + i]; mx = fmaxf(mx, v[i]); }
  red[tid] = mx; __syncthreads();
  for (int s = 512; s > 0; s >>= 1) {
    if (tid < s) red[tid] = fmaxf(red[tid], red[tid + s]);
    __syncthreads();
  }
  mx = red[0]; __syncthreads();
  float sm = 0.f; float e[8];
#pragma unroll
  for (int i = 0; i < 8; i++) { e[i] = __expf(v[i] - mx); sm += e[i]; }
  red[tid] = sm; __syncthreads();
  for (int s = 512; s > 0; s >>= 1) {
    if (tid < s) red[tid] += red[tid + s];
    __syncthreads();
  }
  float rz = 1.f / red[0];
#pragma unroll
  for (int i = 0; i < 8; i++) p[tid * 8 + i] = e[i] * rz;
  if (tid < 256) h_acc[tid] = 0.f;
}

__global__ __launch_bounds__(256) void attn_h(
    const float* __restrict__ mem, const float* __restrict__ p, float* __restrict__ h_acc) {
  int tid = threadIdx.x;
  int r0 = blockIdx.x * 128;
  float acc = 0.f;
  for (int i = 0; i < 128; i++) acc += p[r0 + i] * mem[(long)(r0 + i) * 256 + tid];
  atomicAdd(&h_acc[tid], acc);
}

__global__ __launch_bounds__(128) void attn_o(
    const float* __restrict__ u, const float* __restrict__ h_acc,
    const float* __restrict__ know_W, const float* __restrict__ know_b,
    float* __restrict__ o) {
  __shared__ float uh[256];
  int tid = threadIdx.x;
  uh[tid] = u[tid] + h_acc[tid];
  uh[128 + tid] = u[128 + tid] + h_acc[128 + tid];
  __syncthreads();
  int row = blockIdx.x * 128 + tid;
  float acc = know_b[row];
  for (int k = 0; k < 256; k += 4) {
    float4 w4 = *(const float4*)&know_W[row * 256 + k];
    acc += w4.x * uh[k] + w4.y * uh[k + 1] + w4.z * uh[k + 2] + w4.w * uh[k + 3];
  }
  o[row] = acc;
}

__global__ __launch_bounds__(128) void attn_ov(
    const float* __restrict__ o, const float* __restrict__ Wih0, float* __restrict__ ov) {
  int row = blockIdx.x * 128 + threadIdx.x;
  float acc = 0.f;
  for (int k = 0; k < 1024; k += 4) {
    float4 w4 = *(const float4*)&Wih0[(long)row * 1024 + k];
    float4 o4 = *(const float4*)&o[k];
    acc += w4.x * o4.x + w4.y * o4.y + w4.z * o4.z + w4.w * o4.w;
  }
  ov[row] = acc;
}

// ---------------- LSTM v16: 4 CUs/direction, 256 thr/block, full row per thread ----------------
// grid = 32; active: bid&7 in {0,1}. dir = bid&7, p = bid>>3. Block owns h-elems
// [64p,64p+64) = 256 gate rows. Thread j = one FULL gate row: gate=j>>6, m=j&63,
// 128 half2 weights in VGPR (256-thr tier grants ~204-240 regs; demand ~150).
// 4 waves -> cheap barriers. h-exchange: proven tagged-u64 protocol (3 peers x 32).
__global__ __launch_bounds__(256) void lstm_cc4(
    const unsigned* __restrict__ wp5,    // layer base: [dir<2][p<4][e<128][j<256]
    const float* __restrict__ xg,        // [T][2048] (biases folded)
    const float* __restrict__ extra,     // [2048] rank-1 add or nullptr
    float* __restrict__ out,             // [T][512]
    u64* __restrict__ pay) {             // layer base: [dir*4+p][slot<2][32] u64
  const int bid = blockIdx.x;
  const int xs = bid & 7;
  if (xs >= 2) return;                   // inactive filler blocks
  const int dir = xs, p = bid >> 3;      // p in [0,4)
  const int j = threadIdx.x;             // [0,256)
  const int gate = j >> 6;
  const int m = j & 63;
  const int R = gate * 256 + 64 * p + m; // global gate row

  __shared__ __align__(16) unsigned h2v[128];      // full h packed (h2)
  __shared__ float gact[256];

  const unsigned* base = wp5 + (size_t)dir * 131072 + (size_t)p * 32768;
  unsigned wv[128];
#pragma unroll
  for (int e = 0; e < 128; ++e) wv[e] = base[e * 256 + j];

  float exv = extra ? extra[dir * 1024 + R] : 0.f;
  if (j < 128) h2v[j] = 0u;
  float cst = 0.f;
  __syncthreads();

  const int bi = dir * 4 + p;
  u64* mypay = pay + bi * 64;
  // consuming lanes j<96: pi = j>>5 (0..2), peer p' = pi + (pi>=p)
  const int pi = (j < 96) ? (j >> 5) : 0;
  const int pp = pi + (pi >= p ? 1 : 0);
  u64* peerpay = pay + (dir * 4 + pp) * 64;
  const int pidx = j & 31;

  const float* xp = xg + dir * 1024;
  const int t0 = dir ? (kT - 1) : 0;
  const int dt = dir ? -1 : 1;
  float xc = xp[(long)t0 * 2048 + R] + exv;

  for (int s = 0; s < kT; ++s) {
    const int t = t0 + s * dt;
    float xn_ = 0.f;
    if (s + 1 < kT) xn_ = xp[(long)(t + dt) * 2048 + R];
    // consume 3 peers' h-quarters for step s (tag >= s), per-lane spin
    if (j < 96 && s > 0) {
      u64 v;
      int guard = 0;
      do {
        v = __hip_atomic_load(&peerpay[(s & 1) * 32 + pidx],
                              __ATOMIC_RELAXED, __HIP_MEMORY_SCOPE_AGENT);
      } while ((unsigned)(v >> 32) < (unsigned)s && ++guard < (1 << 18));
      h2v[32 * pp + pidx] = (unsigned)v;
    }
    __syncthreads();   // h2v complete (own quarter written end of prev step)
    // full-K dot: 128 fdot2 over all 32 uint4 of h2v
    const uint4* h4 = (const uint4*)h2v;
    float acc = xc;
#pragma unroll
    for (int c = 0; c < 32; ++c) {
      uint4 hh = h4[c];
      acc = fdot2u(wv[4 * c + 0], hh.x, acc);
      acc = fdot2u(wv[4 * c + 1], hh.y, acc);
      acc = fdot2u(wv[4 * c + 2], hh.z, acc);
      acc = fdot2u(wv[4 * c + 3], hh.w, acc);
    }
    float act = (gate == 2) ? tanh_f(acc) : sigm(acc);
    gact[j] = act;
    __syncthreads();   // gact ready; all h2v reads done
    if (j < 64) {
      float iv  = gact[j];
      float fv  = gact[64 + j];
      float gv  = gact[128 + j];
      float ovv = gact[192 + j];
      cst = fv * cst + iv * gv;
      float h = ovv * tanh_f(cst);
      out[(long)t * 512 + dir * 256 + 64 * p + j] = h;
      float hx = __shfl_xor(h, 1);
      if (!(j & 1)) {
        int idx = j >> 1;                       // 0..31
        unsigned hp = pack_h2(h, hx);
        h2v[32 * p + idx] = hp;                 // own quarter for next step
        u64 tagged = ((u64)(unsigned)(s + 1) << 32) | (u64)hp;
        __hip_atomic_store(&mypay[((s + 1) & 1) * 32 + idx], tagged,
                           __ATOMIC_RELAXED, __HIP_MEMORY_SCOPE_AGENT);
      }
    }
    // no barrier needed: next consume writes disjoint h2v entries; next barrier orders
    xc = xn_ + exv;
  }
}

// ---------------- final row softmax ----------------
__global__ __launch_bounds__(256) void softmax_rows(
    const float* __restrict__ logits, float* __restrict__ outp) {
  int t = blockIdx.x, tid = threadIdx.x;
  __shared__ float red[256];
  const float* lr = logits + (long)t * 4096;
  float v[16];
  float mx = -1e30f;
#pragma unroll
  for (int i = 0; i < 16; i++) { v[i] = lr[tid + 256 * i]; mx = fmaxf(mx, v[i]); }
  red[tid] = mx; __syncthreads();
  for (int s = 128; s > 0; s >>= 1) {
    if (tid < s) red[tid] = fmaxf(red[tid], red[tid + s]);
    __syncthreads();
  }
  mx = red[0]; __syncthreads();
  float sm = 0.f;
#pragma unroll
  for (int i = 0; i < 16; i++) { v[i] = __expf(v[i] - mx); sm += v[i]; }
  red[tid] = sm; __syncthreads();
  for (int s = 128; s > 0; s >>= 1) {
    if (tid < s) red[tid] += red[tid + s];
    __syncthreads();
  }
  float rz = 1.f / red[0];
#pragma unroll
  for (int i = 0; i < 16; i++) outp[(long)t * 4096 + tid + 256 * i] = v[i] * rz;
}

// ---------------- launch ----------------
extern "C" void kernel_launch(void* const* d_in, const int* in_sizes, int n_in,
                              void* d_out, int out_size, void* d_ws, size_t ws_size,
                              hipStream_t stream) {
  const float* c        = (const float*)d_in[0];
  const float* memory   = (const float*)d_in[1];
  const float* enc_Wih  = (const float*)d_in[2];
  const float* enc_Whh  = (const float*)d_in[3];
  const float* enc_bih  = (const float*)d_in[4];
  const float* enc_bhh  = (const float*)d_in[5];
  const float* cenc_Wih = (const float*)d_in[6];
  const float* cenc_Whh = (const float*)d_in[7];
  const float* cenc_bih = (const float*)d_in[8];
  const float* cenc_bhh = (const float*)d_in[9];
  const float* know_W   = (const float*)d_in[10];
  const float* know_b   = (const float*)d_in[11];
  const float* l0_Wih   = (const float*)d_in[12];
  const float* l0_Whh   = (const float*)d_in[13];
  const float* l0_bih   = (const float*)d_in[14];
  const float* l0_bhh   = (const float*)d_in[15];
  const float* l1_Wih   = (const float*)d_in[16];
  const float* l1_Whh   = (const float*)d_in[17];
  const float* l1_bih   = (const float*)d_in[18];
  const float* l1_bhh   = (const float*)d_in[19];
  const float* out_W    = (const float*)d_in[20];
  const float* out_b    = (const float*)d_in[21];

  float* ws = (float*)d_ws;
  float* outp = (float*)d_out;

  float* xgg   = ws;                  // 1,572,864   [T][768]
  float* cW    = ws + 1572864;        // 4,194,304   [T][2048]
  float* wcat  = ws + 5767168;        //   786,432
  float* l0out = ws + 6553600;        // 1,048,576   [T][512]
  float* xg1   = ws + 7602176;        // 4,194,304   [T][2048]
  unsigned* wprep5 = (unsigned*)(ws + 11796480);  // 524,288 u32 (2 MB)
  float* bcat  = ws + 12320768;       // 768
  float* bias0 = ws + 12321536;       // 2048
  float* bias1 = ws + 12323584;       // 2048
  float* u_vec = ws + 12325632;       // 256
  float* d_att = ws + 12325888;       // 8192
  float* p_att = ws + 12334080;       // 8192
  float* h_acc = ws + 12342272;       // 256
  float* o_vec = ws + 12342528;       // 1024
  float* ov    = ws + 12343552;       // 2048
  float* l1out = ws + 12345600;       // 1,048,576  (ends 13,394,176)
  unsigned* wgru = (unsigned*)(ws + 13656320);      // 49,152 u32
  u64* payload = (u64*)(ws + 13705472);             // 1024 u64 (2 layers × 8 blk × 64)
  float* logits = ws;                 // 8,388,608   aliases early regions

  prep_kernel<<<512, 256, 0, stream>>>(enc_Wih, enc_bih, cenc_Wih, cenc_bih,
                                       enc_Whh, cenc_Whh,
                                       l0_Whh, l1_Whh, l0_bih, l0_bhh, l1_bih, l1_bhh,
                                       wcat, bcat, bias0, bias1, wprep5, wgru, payload);
  gemm_bt<<<dim3(768 / 64, 2048 / 64), 256, 0, stream>>>(c, wcat, bcat, xgg, 2048, 768, 1024);
  gemm_bt<<<dim3(2048 / 64, 2048 / 64), 256, 0, stream>>>(c, l0_Wih, bias0, cW, 2048, 2048, 1024);
  gru2<<<4, 256, 0, stream>>>(xgg, c, wgru, enc_Wih, enc_bih, enc_bhh,
                              cenc_Wih, cenc_bih, cenc_bhh,
                              u_vec, outp + kOUT_ELEMS);
  attn_dots<<<256, 256, 0, stream>>>(memory, u_vec, d_att);
  attn_soft<<<1, 1024, 0, stream>>>(d_att, p_att, h_acc);
  attn_h<<<64, 256, 0, stream>>>(memory, p_att, h_acc);
  attn_o<<<8, 128, 0, stream>>>(u_vec, h_acc, know_W, know_b, o_vec);
  attn_ov<<<16, 128, 0, stream>>>(o_vec, l0_Wih, ov);
  lstm_cc4<<<32, 256, 0, stream>>>(wprep5, cW, ov, l0out, payload);
  gemm_bt<<<dim3(2048 / 64, 2048 / 64), 256, 0, stream>>>(l0out, l1_Wih, bias1, xg1, 2048, 2048, 512);
  lstm_cc4<<<32, 256, 0, stream>>>(wprep5 + 262144, xg1, nullptr, l1out, payload + 512);
  gemm_bt<<<dim3(4096 / 64, 2048 / 64), 256, 0, stream>>>(l1out, out_W, out_b, logits, 2048, 4096, 512);
  softmax_rows<<<2048, 256, 0, stream>>>(logits, outp);
}

// Round 17
// 7330.912 us; speedup vs baseline: 1.7741x; 1.0094x over previous
//
#include <hip/hip_runtime.h>
#include <hip/hip_bf16.h>

// ---------------- constants ----------------
static constexpr int kT    = 2048;
static constexpr int kOUT_ELEMS = 2048 * 4096;   // output 0 size

typedef _Float16 half2_t __attribute__((ext_vector_type(2)));
typedef unsigned long long u64;

__device__ __forceinline__ unsigned pack_h2(float a, float b) {
  half2_t h{(_Float16)a, (_Float16)b};
  return __builtin_bit_cast(unsigned, h);
}
__device__ __forceinline__ float fdot2u(unsigned a, unsigned b, float c) {
  return __builtin_amdgcn_fdot2(__builtin_bit_cast(half2_t, a),
                                __builtin_bit_cast(half2_t, b), c, false);
}
__device__ __forceinline__ float sigm(float x) {
  return 1.f / (1.f + __expf(-x));
}
__device__ __forceinline__ float tanh_f(float x) {
  float ax = fabsf(x);
  float e = __expf(-2.f * ax);
  float r = (1.f - e) / (1.f + e);
  return x < 0.f ? -r : r;
}

// ---------------- K0: prep ----------------
// wprep5 [ld<4][p<4][e<128][j<256]: half2 col e of row R for thread j of block (ld,p);
//   gate=j>>6, m=j&63, R=gate*256+64p+m, col=2e. (per ld: 131072 u32)
// wgru [g2<2][e<64][row<384]; payload tags zeroed each launch.
__global__ __launch_bounds__(256) void prep_kernel(
    const float* __restrict__ enc_Wih, const float* __restrict__ enc_bih,
    const float* __restrict__ cenc_Wih, const float* __restrict__ cenc_bih,
    const float* __restrict__ enc_Whh, const float* __restrict__ cenc_Whh,
    const float* __restrict__ l0_Whh, const float* __restrict__ l1_Whh,
    const float* __restrict__ l0_bih, const float* __restrict__ l0_bhh,
    const float* __restrict__ l1_bih, const float* __restrict__ l1_bhh,
    float* __restrict__ wcat, float* __restrict__ bcat,
    float* __restrict__ bias0, float* __restrict__ bias1,
    unsigned* __restrict__ wprep5, unsigned* __restrict__ wgru,
    u64* __restrict__ payz) {
  int idx0 = blockIdx.x * blockDim.x + threadIdx.x;
  int stride = gridDim.x * blockDim.x;
  for (int i = idx0; i < 1024; i += stride) payz[i] = 0ull;   // re-zero every launch
  for (int i = idx0; i < 768 * 1024; i += stride) {
    int r = i >> 10, cc = i & 1023;
    wcat[i] = (r < 384) ? enc_Wih[r * 1024 + cc] : cenc_Wih[(r - 384) * 1024 + cc];
  }
  for (int i = idx0; i < 768; i += stride)
    bcat[i] = (i < 384) ? enc_bih[i] : cenc_bih[i - 384];
  for (int i = idx0; i < 2048; i += stride) {
    bias0[i] = l0_bih[i] + l0_bhh[i];
    bias1[i] = l1_bih[i] + l1_bhh[i];
  }
  for (int i = idx0; i < 4 * 4 * 128 * 256; i += stride) {
    int j = i & 255;
    int e = (i >> 8) & 127;
    int p = (i >> 15) & 3;
    int ld = i >> 17;  // layer*2 + dir
    const float* W = (ld < 2 ? l0_Whh : l1_Whh) + (ld & 1) * 1024 * 256;
    int gate = j >> 6, m = j & 63;
    int R = gate * 256 + 64 * p + m;
    wprep5[i] = pack_h2(W[R * 256 + 2 * e], W[R * 256 + 2 * e + 1]);
  }
  for (int i = idx0; i < 2 * 64 * 384; i += stride) {
    int row = i % 384;
    int e = (i / 384) & 63;
    int g2 = i / (64 * 384);
    const float* W = g2 ? cenc_Whh : enc_Whh;   // dir0 at base
    wgru[i] = pack_h2(W[row * 128 + 2 * e], W[row * 128 + 2 * e + 1]);
  }
}

// ---------------- fp32 tiled GEMM: C[M][N] = A[M][K] * B[N][K]^T + bias[N] ----------------
__global__ __launch_bounds__(256) void gemm_bt(
    const float* __restrict__ A, const float* __restrict__ B,
    const float* __restrict__ bias, float* __restrict__ C,
    int M, int N, int K) {
  __shared__ float As[16][68];
  __shared__ float Bs[16][68];
  int tid = threadIdx.x;
  int tx = tid & 15, ty = tid >> 4;
  int m0 = blockIdx.y * 64, n0 = blockIdx.x * 64;
  int lr = tid >> 2;
  int lc = (tid & 3) << 2;
  float acc[4][4] = {};
  const float* Ap = A + (long)(m0 + lr) * K + lc;
  const float* Bp = B + (long)(n0 + lr) * K + lc;
  for (int k0 = 0; k0 < K; k0 += 16) {
    float4 a4 = *(const float4*)(Ap + k0);
    float4 b4 = *(const float4*)(Bp + k0);
    __syncthreads();
    As[lc + 0][lr] = a4.x; As[lc + 1][lr] = a4.y; As[lc + 2][lr] = a4.z; As[lc + 3][lr] = a4.w;
    Bs[lc + 0][lr] = b4.x; Bs[lc + 1][lr] = b4.y; Bs[lc + 2][lr] = b4.z; Bs[lc + 3][lr] = b4.w;
    __syncthreads();
#pragma unroll
    for (int kk = 0; kk < 16; kk++) {
      float4 ra = *(const float4*)&As[kk][ty << 2];
      float4 rb = *(const float4*)&Bs[kk][tx << 2];
      float av[4] = {ra.x, ra.y, ra.z, ra.w};
      float bv[4] = {rb.x, rb.y, rb.z, rb.w};
#pragma unroll
      for (int i = 0; i < 4; i++)
#pragma unroll
        for (int jj = 0; jj < 4; jj++)
          acc[i][jj] += av[i] * bv[jj];
    }
  }
#pragma unroll
  for (int i = 0; i < 4; i++) {
    int m = m0 + (ty << 2) + i;
#pragma unroll
    for (int jj = 0; jj < 4; jj++) {
      int n = n0 + (tx << 2) + jj;
      C[(long)m * N + n] = acc[i][jj] + (bias ? bias[n] : 0.f);
    }
  }
}

// ---------------- GRU: 256 threads, fp16 weights VGPR-pinned ----------------
__global__ __launch_bounds__(256) void gru2(
    const float* __restrict__ xgg,   // [T][768]
    const float* __restrict__ c_in,  // [T][1024]
    const unsigned* __restrict__ wgru,
    const float* __restrict__ enc_Wih, const float* __restrict__ enc_bih,
    const float* __restrict__ enc_bhh,
    const float* __restrict__ cenc_Wih, const float* __restrict__ cenc_bih,
    const float* __restrict__ cenc_bhh,
    float* __restrict__ u_out, float* __restrict__ cmem_out) {
  int b = blockIdx.x, j = threadIdx.x;
  __shared__ __align__(16) unsigned h2g[64];
  __shared__ float zs[128];
  const bool dual = j < 128;
  if (b < 2) {
    const unsigned* wg = wgru + b * (64 * 384);
    const float* bhh = b ? cenc_bhh : enc_bhh;
    unsigned w0[64], w1[64];
#pragma unroll
    for (int e = 0; e < 64; ++e) w0[e] = wg[e * 384 + j];
#pragma unroll
    for (int e = 0; e < 64; ++e) asm volatile("" : "+v"(w0[e]));  // pin: no remat
    float bh0 = bhh[j], bh1 = 0.f;
    if (dual) {
#pragma unroll
      for (int e = 0; e < 64; ++e) w1[e] = wg[e * 384 + 256 + j];
#pragma unroll
      for (int e = 0; e < 64; ++e) asm volatile("" : "+v"(w1[e]));
      bh1 = bhh[256 + j];
    }
    if (j < 64) h2g[j] = 0u;
    float hreg = 0.f;
    __syncthreads();
    const float* xp = xgg + b * 384;
    float x0 = xp[j];
    float x1 = dual ? xp[256 + j] : 0.f;
    for (int t = 0; t < kT; ++t) {
      float x0n = 0.f, x1n = 0.f;
      if (t + 1 < kT) {
        x0n = xp[(t + 1) * 768 + j];
        if (dual) x1n = xp[(t + 1) * 768 + 256 + j];
      }
      const uint4* h4 = (const uint4*)h2g;
      float a0 = 0.f, a1 = 0.f;
#pragma unroll
      for (int k = 0; k < 16; ++k) {
        uint4 hh = h4[k];
        a0 = fdot2u(w0[4 * k + 0], hh.x, a0);
        a0 = fdot2u(w0[4 * k + 1], hh.y, a0);
        a0 = fdot2u(w0[4 * k + 2], hh.z, a0);
        a0 = fdot2u(w0[4 * k + 3], hh.w, a0);
        if (dual) {
          a1 = fdot2u(w1[4 * k + 0], hh.x, a1);
          a1 = fdot2u(w1[4 * k + 1], hh.y, a1);
          a1 = fdot2u(w1[4 * k + 2], hh.z, a1);
          a1 = fdot2u(w1[4 * k + 3], hh.w, a1);
        }
      }
      if (!dual) zs[j - 128] = sigm(x0 + a0 + bh0);
      __syncthreads();
      if (dual) {
        float r = sigm(x0 + a0 + bh0);
        float n = tanh_f(x1 + r * (a1 + bh1));
        float z = zs[j];
        hreg = (1.f - z) * n + z * hreg;
        float hx = __shfl_xor(hreg, 1);
        if (!(j & 1)) h2g[j >> 1] = pack_h2(hreg, hx);
      }
      __syncthreads();
      x0 = x0n; x1 = x1n;
    }
    if (dual) { if (b == 0) u_out[j] = hreg; else cmem_out[j] = hreg; }
  } else {
    const float* Wih = ((b == 2) ? enc_Wih : cenc_Wih) + 384 * 1024;
    const float* bih = ((b == 2) ? enc_bih : cenc_bih) + 384;
    const float* bhh = ((b == 2) ? enc_bhh : cenc_bhh) + 384;
    const float* crow = c_in + (long)(kT - 1) * 1024;
    float a0 = bih[j], a1 = 0.f;
    {
      const float* wr = Wih + (long)j * 1024;
      for (int k = 0; k < 1024; k += 4) {
        float4 cv = *(const float4*)&crow[k];
        float4 wv = *(const float4*)&wr[k];
        a0 += cv.x * wv.x + cv.y * wv.y + cv.z * wv.z + cv.w * wv.w;
      }
    }
    if (dual) {
      a1 = bih[256 + j];
      const float* wr = Wih + (long)(256 + j) * 1024;
      for (int k = 0; k < 1024; k += 4) {
        float4 cv = *(const float4*)&crow[k];
        float4 wv = *(const float4*)&wr[k];
        a1 += cv.x * wv.x + cv.y * wv.y + cv.z * wv.z + cv.w * wv.w;
      }
    }
    if (!dual) zs[j - 128] = sigm(a0 + bhh[j]);
    __syncthreads();
    if (dual) {
      float r = sigm(a0 + bhh[j]);
      float n = tanh_f(a1 + r * bhh[256 + j]);
      float z = zs[j];
      float h = (1.f - z) * n;
      if (b == 2) u_out[128 + j] = h; else cmem_out[128 + j] = h;
    }
  }
}

// ---------------- attention ----------------
__global__ __launch_bounds__(256) void attn_dots(
    const float* __restrict__ mem, const float* __restrict__ u, float* __restrict__ d) {
  __shared__ float us[256];
  int tid = threadIdx.x;
  us[tid] = u[tid];
  __syncthreads();
  int g = tid >> 3, l8 = tid & 7;
  int row = blockIdx.x * 32 + g;
  const float* mr = mem + (long)row * 256 + l8 * 32;
  float p = 0.f;
#pragma unroll
  for (int k = 0; k < 32; k += 4) {
    float4 m4 = *(const float4*)&mr[k];
    p += m4.x * us[l8 * 32 + k] + m4.y * us[l8 * 32 + k + 1] +
         m4.z * us[l8 * 32 + k + 2] + m4.w * us[l8 * 32 + k + 3];
  }
  p += __shfl_down(p, 4);
  p += __shfl_down(p, 2);
  p += __shfl_down(p, 1);
  if (l8 == 0) d[row] = p;
}

__global__ __launch_bounds__(1024) void attn_soft(
    const float* __restrict__ d, float* __restrict__ p, float* __restrict__ h_acc) {
  __shared__ float red[1024];
  int tid = threadIdx.x;
  float v[8];
  float mx = -1e30f;
#pragma unroll
  for (int i = 0; i < 8; i++) { v[i] = d[tid * 8 + i]; mx = fmaxf(mx, v[i]); }
  red[tid] = mx; __syncthreads();
  for (int s = 512; s > 0; s >>= 1) {
    if (tid < s) red[tid] = fmaxf(red[tid], red[tid + s]);
    __syncthreads();
  }
  mx = red[0]; __syncthreads();
  float sm = 0.f; float e[8];
#pragma unroll
  for (int i = 0; i < 8; i++) { e[i] = __expf(v[i] - mx); sm += e[i]; }
  red[tid] = sm; __syncthreads();
  for (int s = 512; s > 0; s >>= 1) {
    if (tid < s) red[tid] += red[tid + s];
    __syncthreads();
  }
  float rz = 1.f / red[0];
#pragma unroll
  for (int i = 0; i < 8; i++) p[tid * 8 + i] = e[i] * rz;
  if (tid < 256) h_acc[tid] = 0.f;
}

__global__ __launch_bounds__(256) void attn_h(
    const float* __restrict__ mem, const float* __restrict__ p, float* __restrict__ h_acc) {
  int tid = threadIdx.x;
  int r0 = blockIdx.x * 128;
  float acc = 0.f;
  for (int i = 0; i < 128; i++) acc += p[r0 + i] * mem[(long)(r0 + i) * 256 + tid];
  atomicAdd(&h_acc[tid], acc);
}

__global__ __launch_bounds__(128) void attn_o(
    const float* __restrict__ u, const float* __restrict__ h_acc,
    const float* __restrict__ know_W, const float* __restrict__ know_b,
    float* __restrict__ o) {
  __shared__ float uh[256];
  int tid = threadIdx.x;
  uh[tid] = u[tid] + h_acc[tid];
  uh[128 + tid] = u[128 + tid] + h_acc[128 + tid];
  __syncthreads();
  int row = blockIdx.x * 128 + tid;
  float acc = know_b[row];
  for (int k = 0; k < 256; k += 4) {
    float4 w4 = *(const float4*)&know_W[row * 256 + k];
    acc += w4.x * uh[k] + w4.y * uh[k + 1] + w4.z * uh[k + 2] + w4.w * uh[k + 3];
  }
  o[row] = acc;
}

__global__ __launch_bounds__(128) void attn_ov(
    const float* __restrict__ o, const float* __restrict__ Wih0, float* __restrict__ ov) {
  int row = blockIdx.x * 128 + threadIdx.x;
  float acc = 0.f;
  for (int k = 0; k < 1024; k += 4) {
    float4 w4 = *(const float4*)&Wih0[(long)row * 1024 + k];
    float4 o4 = *(const float4*)&o[k];
    acc += w4.x * o4.x + w4.y * o4.y + w4.z * o4.z + w4.w * o4.w;
  }
  ov[row] = acc;
}

// ---------------- LSTM v17: 4 CUs/direction, 256 thr, VGPR-PINNED weights ----------------
// Identical to v16 except the weight array is pinned with an opaque asm touch so the
// compiler cannot rematerialize the loop-invariant loads (v16: VGPR=84, weights
// re-streamed from L2 every step at ~38 B/cy). Demand ~155 regs <= 204-240 tier.
__global__ __launch_bounds__(256) void lstm_cc4(
    const unsigned* __restrict__ wp5,    // layer base: [dir<2][p<4][e<128][j<256]
    const float* __restrict__ xg,        // [T][2048] (biases folded)
    const float* __restrict__ extra,     // [2048] rank-1 add or nullptr
    float* __restrict__ out,             // [T][512]
    u64* __restrict__ pay) {             // layer base: [dir*4+p][slot<2][32] u64
  const int bid = blockIdx.x;
  const int xs = bid & 7;
  if (xs >= 2) return;                   // inactive filler blocks
  const int dir = xs, p = bid >> 3;      // p in [0,4)
  const int j = threadIdx.x;             // [0,256)
  const int gate = j >> 6;
  const int m = j & 63;
  const int R = gate * 256 + 64 * p + m; // global gate row

  __shared__ __align__(16) unsigned h2v[128];      // full h packed (h2)
  __shared__ float gact[256];

  const unsigned* base = wp5 + (size_t)dir * 131072 + (size_t)p * 32768;
  unsigned wv[128];
#pragma unroll
  for (int e = 0; e < 128; ++e) wv[e] = base[e * 256 + j];
#pragma unroll
  for (int e = 0; e < 128; ++e) asm volatile("" : "+v"(wv[e]));  // pin: no remat

  float exv = extra ? extra[dir * 1024 + R] : 0.f;
  if (j < 128) h2v[j] = 0u;
  float cst = 0.f;
  __syncthreads();

  const int bi = dir * 4 + p;
  u64* mypay = pay + bi * 64;
  // consuming lanes j<96: pi = j>>5 (0..2), peer p' = pi + (pi>=p)
  const int pi = (j < 96) ? (j >> 5) : 0;
  const int pp = pi + (pi >= p ? 1 : 0);
  u64* peerpay = pay + (dir * 4 + pp) * 64;
  const int pidx = j & 31;

  const float* xp = xg + dir * 1024;
  const int t0 = dir ? (kT - 1) : 0;
  const int dt = dir ? -1 : 1;
  float xc = xp[(long)t0 * 2048 + R] + exv;

  for (int s = 0; s < kT; ++s) {
    const int t = t0 + s * dt;
    float xn_ = 0.f;
    if (s + 1 < kT) xn_ = xp[(long)(t + dt) * 2048 + R];
    // consume 3 peers' h-quarters for step s (tag >= s), per-lane spin
    if (j < 96 && s > 0) {
      u64 v;
      int guard = 0;
      do {
        v = __hip_atomic_load(&peerpay[(s & 1) * 32 + pidx],
                              __ATOMIC_RELAXED, __HIP_MEMORY_SCOPE_AGENT);
      } while ((unsigned)(v >> 32) < (unsigned)s && ++guard < (1 << 18));
      h2v[32 * pp + pidx] = (unsigned)v;
    }
    __syncthreads();   // h2v complete (own quarter written end of prev step)
    // full-K dot: 128 fdot2 over all 32 uint4 of h2v
    const uint4* h4 = (const uint4*)h2v;
    float acc = xc;
#pragma unroll
    for (int c = 0; c < 32; ++c) {
      uint4 hh = h4[c];
      acc = fdot2u(wv[4 * c + 0], hh.x, acc);
      acc = fdot2u(wv[4 * c + 1], hh.y, acc);
      acc = fdot2u(wv[4 * c + 2], hh.z, acc);
      acc = fdot2u(wv[4 * c + 3], hh.w, acc);
    }
    float act = (gate == 2) ? tanh_f(acc) : sigm(acc);
    gact[j] = act;
    __syncthreads();   // gact ready; all h2v reads done
    if (j < 64) {
      float iv  = gact[j];
      float fv  = gact[64 + j];
      float gv  = gact[128 + j];
      float ovv = gact[192 + j];
      cst = fv * cst + iv * gv;
      float h = ovv * tanh_f(cst);
      out[(long)t * 512 + dir * 256 + 64 * p + j] = h;
      float hx = __shfl_xor(h, 1);
      if (!(j & 1)) {
        int idx = j >> 1;                       // 0..31
        unsigned hp = pack_h2(h, hx);
        h2v[32 * p + idx] = hp;                 // own quarter for next step
        u64 tagged = ((u64)(unsigned)(s + 1) << 32) | (u64)hp;
        __hip_atomic_store(&mypay[((s + 1) & 1) * 32 + idx], tagged,
                           __ATOMIC_RELAXED, __HIP_MEMORY_SCOPE_AGENT);
      }
    }
    // no barrier needed: next consume writes disjoint h2v entries; next barrier orders
    xc = xn_ + exv;
  }
}

// ---------------- final row softmax ----------------
__global__ __launch_bounds__(256) void softmax_rows(
    const float* __restrict__ logits, float* __restrict__ outp) {
  int t = blockIdx.x, tid = threadIdx.x;
  __shared__ float red[256];
  const float* lr = logits + (long)t * 4096;
  float v[16];
  float mx = -1e30f;
#pragma unroll
  for (int i = 0; i < 16; i++) { v[i] = lr[tid + 256 * i]; mx = fmaxf(mx, v[i]); }
  red[tid] = mx; __syncthreads();
  for (int s = 128; s > 0; s >>= 1) {
    if (tid < s) red[tid] = fmaxf(red[tid], red[tid + s]);
    __syncthreads();
  }
  mx = red[0]; __syncthreads();
  float sm = 0.f;
#pragma unroll
  for (int i = 0; i < 16; i++) { v[i] = __expf(v[i] - mx); sm += v[i]; }
  red[tid] = sm; __syncthreads();
  for (int s = 128; s > 0; s >>= 1) {
    if (tid < s) red[tid] += red[tid + s];
    __syncthreads();
  }
  float rz = 1.f / red[0];
#pragma unroll
  for (int i = 0; i < 16; i++) outp[(long)t * 4096 + tid + 256 * i] = v[i] * rz;
}

// ---------------- launch ----------------
extern "C" void kernel_launch(void* const* d_in, const int* in_sizes, int n_in,
                              void* d_out, int out_size, void* d_ws, size_t ws_size,
                              hipStream_t stream) {
  const float* c        = (const float*)d_in[0];
  const float* memory   = (const float*)d_in[1];
  const float* enc_Wih  = (const float*)d_in[2];
  const float* enc_Whh  = (const float*)d_in[3];
  const float* enc_bih  = (const float*)d_in[4];
  const float* enc_bhh  = (const float*)d_in[5];
  const float* cenc_Wih = (const float*)d_in[6];
  const float* cenc_Whh = (const float*)d_in[7];
  const float* cenc_bih = (const float*)d_in[8];
  const float* cenc_bhh = (const float*)d_in[9];
  const float* know_W   = (const float*)d_in[10];
  const float* know_b   = (const float*)d_in[11];
  const float* l0_Wih   = (const float*)d_in[12];
  const float* l0_Whh   = (const float*)d_in[13];
  const float* l0_bih   = (const float*)d_in[14];
  const float* l0_bhh   = (const float*)d_in[15];
  const float* l1_Wih   = (const float*)d_in[16];
  const float* l1_Whh   = (const float*)d_in[17];
  const float* l1_bih   = (const float*)d_in[18];
  const float* l1_bhh   = (const float*)d_in[19];
  const float* out_W    = (const float*)d_in[20];
  const float* out_b    = (const float*)d_in[21];

  float* ws = (float*)d_ws;
  float* outp = (float*)d_out;

  float* xgg   = ws;                  // 1,572,864   [T][768]
  float* cW    = ws + 1572864;        // 4,194,304   [T][2048]
  float* wcat  = ws + 5767168;        //   786,432
  float* l0out = ws + 6553600;        // 1,048,576   [T][512]
  float* xg1   = ws + 7602176;        // 4,194,304   [T][2048]
  unsigned* wprep5 = (unsigned*)(ws + 11796480);  // 524,288 u32 (2 MB)
  float* bcat  = ws + 12320768;       // 768
  float* bias0 = ws + 12321536;       // 2048
  float* bias1 = ws + 12323584;       // 2048
  float* u_vec = ws + 12325632;       // 256
  float* d_att = ws + 12325888;       // 8192
  float* p_att = ws + 12334080;       // 8192
  float* h_acc = ws + 12342272;       // 256
  float* o_vec = ws + 12342528;       // 1024
  float* ov    = ws + 12343552;       // 2048
  float* l1out = ws + 12345600;       // 1,048,576  (ends 13,394,176)
  unsigned* wgru = (unsigned*)(ws + 13656320);      // 49,152 u32
  u64* payload = (u64*)(ws + 13705472);             // 1024 u64 (2 layers × 8 blk × 64)
  float* logits = ws;                 // 8,388,608   aliases early regions

  prep_kernel<<<512, 256, 0, stream>>>(enc_Wih, enc_bih, cenc_Wih, cenc_bih,
                                       enc_Whh, cenc_Whh,
                                       l0_Whh, l1_Whh, l0_bih, l0_bhh, l1_bih, l1_bhh,
                                       wcat, bcat, bias0, bias1, wprep5, wgru, payload);
  gemm_bt<<<dim3(768 / 64, 2048 / 64), 256, 0, stream>>>(c, wcat, bcat, xgg, 2048, 768, 1024);
  gemm_bt<<<dim3(2048 / 64, 2048 / 64), 256, 0, stream>>>(c, l0_Wih, bias0, cW, 2048, 2048, 1024);
  gru2<<<4, 256, 0, stream>>>(xgg, c, wgru, enc_Wih, enc_bih, enc_bhh,
                              cenc_Wih, cenc_bih, cenc_bhh,
                              u_vec, outp + kOUT_ELEMS);
  attn_dots<<<256, 256, 0, stream>>>(memory, u_vec, d_att);
  attn_soft<<<1, 1024, 0, stream>>>(d_att, p_att, h_acc);
  attn_h<<<64, 256, 0, stream>>>(memory, p_att, h_acc);
  attn_o<<<8, 128, 0, stream>>>(u_vec, h_acc, know_W, know_b, o_vec);
  attn_ov<<<16, 128, 0, stream>>>(o_vec, l0_Wih, ov);
  lstm_cc4<<<32, 256, 0, stream>>>(wprep5, cW, ov, l0out, payload);
  gemm_bt<<<dim3(2048 / 64, 2048 / 64), 256, 0, stream>>>(l0out, l1_Wih, bias1, xg1, 2048, 2048, 512);
  lstm_cc4<<<32, 256, 0, stream>>>(wprep5 + 262144, xg1, nullptr, l1out, payload + 512);
  gemm_bt<<<dim3(4096 / 64, 2048 / 64), 256, 0, stream>>>(l1out, out_W, out_b, logits, 2048, 4096, 512);
  softmax_rows<<<2048, 256, 0, stream>>>(logits, outp);
}